// Round 15
// baseline (108.795 us; speedup 1.0000x reference)
//
#include <hip/hip_runtime.h>

#define HH 256
#define WW 256
#define CC 32
#define HWSZ (HH * WW)
#define IMGSZ (CC * HWSZ)
#define NIMG 8
#define EPSV 1e-8f
#define NCH (CC / 2)   // channels per lane (2-way channel split)

__device__ __forceinline__ void acc_pass1(const float v[3][6],
                                          float sq[3][6], float dotv[8][4])
{
#pragma unroll
    for (int r = 0; r < 3; ++r)
#pragma unroll
        for (int j = 0; j < 6; ++j) sq[r][j] = fmaf(v[r][j], v[r][j], sq[r][j]);
    int d = 0;
#pragma unroll
    for (int dyi = 0; dyi < 3; ++dyi)
#pragma unroll
        for (int dxi = 0; dxi < 3; ++dxi) {
            if (dyi == 1 && dxi == 1) continue;
#pragma unroll
            for (int i = 0; i < 4; ++i)
                dotv[d][i] = fmaf(v[1][i + 1], v[dyi][i + dxi], dotv[d][i]);
            ++d;
        }
}

__device__ __forceinline__ void acc_pass2(const float v[3][6],
                                          const float w[8][4], float o[4])
{
    int d = 0;
#pragma unroll
    for (int dyi = 0; dyi < 3; ++dyi)
#pragma unroll
        for (int dxi = 0; dxi < 3; ++dxi) {
            if (dyi == 1 && dxi == 1) continue;
#pragma unroll
            for (int i = 0; i < 4; ++i)
                o[i] = fmaf(w[d][i], v[dyi][i + dxi], o[i]);
            ++d;
        }
}

// Async global -> LDS, 16 B per lane. LDS dest is wave-uniform (HW adds
// lane*16); global source is per-lane.
__device__ __forceinline__ void gload16(const void* g, void* l)
{
    __builtin_amdgcn_global_load_lds(
        (const __attribute__((address_space(1))) void*)g,
        (__attribute__((address_space(3))) void*)l, 16, 0, 0);
}

// Stage a PAIR of channels (CH0, CH0+1), both halves, into slab pair at byte
// offset POFF. 4 gload16 = 4 vmcnt ticks. Each wave stages slab row `wave`.
#define STAGE2(POFF, CH0) { \
    gload16(gsrc0 + (size_t)(CH0) * HWSZ,        ldst0 + (POFF)); \
    gload16(gsrc0 + (size_t)((CH0) + 16) * HWSZ, ldst0 + (POFF) + 4096); \
    gload16(gsrc0 + (size_t)((CH0) + 1) * HWSZ,  ldst0 + (POFF) + 8192); \
    gload16(gsrc0 + (size_t)((CH0) + 17) * HWSZ, ldst0 + (POFF) + 12288); }

// Counted-vmcnt wait + raw barrier (NOT __syncthreads: that drains vmcnt(0)
// and kills the pipeline).
#define WAITB(VM) { asm volatile("s_waitcnt vmcnt(" #VM ")" ::: "memory"); \
                    __builtin_amdgcn_s_barrier(); }

// Read this lane's 3x6 window from the 8KB slot at byte offset OFFB.
#define LOADV(OFFB, VV) { \
    const char* sp_ = slabb + (OFFB); \
    _Pragma("unroll") \
    for (int r_ = 0; r_ < 3; ++r_) { \
        float4 m_ = *(const float4*)(sp_ + bM + r_ * 1024); \
        float e_ = 0.f; \
        if (edge) e_ = *(const float*)(sp_ + bE + r_ * 1024); \
        const float lu_ = __shfl_up(m_.w, 1); \
        const float rd_ = __shfl_down(m_.x, 1); \
        const bool ok_ = rowok[r_]; \
        VV[r_][0] = (ok_ && xl) ? ((tx == 0)  ? e_ : lu_) : 0.f; \
        VV[r_][1] = ok_ ? m_.x : 0.f; \
        VV[r_][2] = ok_ ? m_.y : 0.f; \
        VV[r_][3] = ok_ ? m_.z : 0.f; \
        VV[r_][4] = ok_ ? m_.w : 0.f; \
        VV[r_][5] = (ok_ && xr) ? ((tx == 31) ? e_ : rd_) : 0.f; \
    } }

#define ROT3(P) { P = (P == 2) ? 0 : P + 1; }

// Lane mapping: half = lane>>5 (16 channels each), tx = lane&31 (4 px each).
// Wave = 128 px (half row); block = 4 waves = 2 rows. 6 slabs (3 pairs),
// 2 channels consumed per barrier, stage targets the pair consumed LAST
// iteration (race-free behind this iteration's barrier).
template <bool YEDGE, bool COMPUTE_NEXT>
__device__ __forceinline__ void step_body(const float* __restrict__ F,
                                          float* __restrict__ Fn,
                                          float* __restrict__ simout,
                                          char* slabb, int b, int rowblk, int tid)
{
    const int wave = tid >> 6;
    const int lane = tid & 63;
    const int half = lane >> 5;            // channel half
    const int tx   = lane & 31;            // px group
    const int y0   = rowblk * 2;
    const int y    = y0 + (wave >> 1);
    const int x0   = (wave & 1) * 128 + (tx << 2);
    const int c0   = half * NCH;

    const bool ym = YEDGE ? (y > 0) : true;
    const bool yp = YEDGE ? (y < HH - 1) : true;
    const bool xl = x0 > 0, xr = x0 < WW - 4;
    const bool rowok[3] = { ym, true, yp };
    const bool colok[6] = { xl, true, true, true, true, xr };

    const float* Fb = F + (size_t)b * IMGSZ;

    // Staging invariants: this wave stages slab row `wave` = image row clamp(y0-1+wave).
    int arow = y0 - 1 + wave;
    if (YEDGE) arow = arow < 0 ? 0 : (arow > HH - 1 ? HH - 1 : arow);
    const float* gsrc0 = Fb + arow * WW + (lane << 2);
    char* ldst0 = slabb + wave * 1024;     // wave-uniform; +pair/half offsets in STAGE2

    // ds-read invariants: rows (wave>>1)+{0,1,2} of own half.
    const int rbase = half * 4096 + (wave >> 1) * 1024;
    const int bM = rbase + x0 * 4;
    const int bL = rbase + (xl ? x0 * 4 - 4 : 0);
    const int bR = rbase + (xr ? x0 * 4 + 16 : 1020);
    const bool edge = (tx == 0) || (tx == 31);
    const int bE = (tx == 31) ? bR : bL;

    // ---------------- Pass 1: partial norms + dots over 16 channels ----------
    float sq[3][6];
    float dotv[8][4];
#pragma unroll
    for (int r = 0; r < 3; ++r)
#pragma unroll
        for (int j = 0; j < 6; ++j) sq[r][j] = 0.f;
#pragma unroll
    for (int d = 0; d < 8; ++d)
#pragma unroll
        for (int i = 0; i < 4; ++i) dotv[d][i] = 0.f;

    STAGE2(0, 0) STAGE2(16384, 2)          // pairs 0,1 = channels 0..3
    int po = 0;                            // consume-pair rotator

#pragma unroll 1
    for (int k = 0; k < (COMPUTE_NEXT ? 8 : 6); ++k) {
        const int qo = (po == 0) ? 2 : po - 1;     // stage pair (consumed last iter)
        WAITB(4)
        float v[3][6];
        LOADV(po * 16384, v)        acc_pass1(v, sq, dotv);
        LOADV(po * 16384 + 8192, v) acc_pass1(v, sq, dotv);
        STAGE2(qo * 16384, (2 * k + 4) & 15)       // slots 2k+4,2k+5
        ROT3(po)
    }
    if (!COMPUTE_NEXT) {                   // peeled tail: channels 12..15
        { WAITB(4) float v[3][6];
          LOADV(po * 16384, v)        acc_pass1(v, sq, dotv);
          LOADV(po * 16384 + 8192, v) acc_pass1(v, sq, dotv); ROT3(po) }
        { WAITB(0) float v[3][6];
          LOADV(po * 16384, v)        acc_pass1(v, sq, dotv);
          LOADV(po * 16384 + 8192, v) acc_pass1(v, sq, dotv); }
    }

    // Merge the two channel halves (lane bit 5).
#pragma unroll
    for (int r = 0; r < 3; ++r)
#pragma unroll
        for (int j = 0; j < 6; ++j) sq[r][j] += __shfl_xor(sq[r][j], 32);
#pragma unroll
    for (int d = 0; d < 8; ++d)
#pragma unroll
        for (int i = 0; i < 4; ++i) dotv[d][i] += __shfl_xor(dotv[d][i], 32);

    float nrm[3][6];
#pragma unroll
    for (int r = 0; r < 3; ++r)
#pragma unroll
        for (int j = 0; j < 6; ++j) nrm[r][j] = __builtin_amdgcn_sqrtf(sq[r][j]);

    float w[8][4];
    float simarr[4];
#pragma unroll
    for (int i = 0; i < 4; ++i) {
        float s[8];
        const float cn = nrm[1][i + 1];
        float tot = 0.f, cnt = 0.f;
        int d = 0;
#pragma unroll
        for (int dyi = 0; dyi < 3; ++dyi)
#pragma unroll
            for (int dxi = 0; dxi < 3; ++dxi) {
                if (dyi == 1 && dxi == 1) continue;
                const bool m = rowok[dyi] && colok[i + dxi];
                const float den = fmaxf(cn * nrm[dyi][i + dxi], EPSV);
                const float cs = dotv[d][i] * __builtin_amdgcn_rcpf(den);
                s[d] = m ? cs : 0.f;
                tot += s[d];
                cnt += m ? 1.f : 0.f;
                ++d;
            }
        simarr[i] = tot * __builtin_amdgcn_rcpf(cnt);
        if (COMPUTE_NEXT) {
            float mx = s[0];
#pragma unroll
            for (int d2 = 1; d2 < 8; ++d2) mx = fmaxf(mx, s[d2]);
            float wsum = 0.f;
#pragma unroll
            for (int d2 = 0; d2 < 8; ++d2) { w[d2][i] = __expf(s[d2] - mx); wsum += w[d2][i]; }
            const float inv = __builtin_amdgcn_rcpf(wsum);
#pragma unroll
            for (int d2 = 0; d2 < 8; ++d2) w[d2][i] *= inv;
        }
    }
    if (half == 0) {
        float4 simv = { simarr[0], simarr[1], simarr[2], simarr[3] };
        *reinterpret_cast<float4*>(simout + b * HWSZ + y * WW + x0) = simv;
    }

    // ---------------- Pass 2: weighted neighbor average (own 16 channels) ----
    // Slots 16..31 (channels 0..15 re-staged; 16,17 landed, 18,19 in flight).
    if (COMPUTE_NEXT) {
        float* outp = Fn + (size_t)b * IMGSZ + (size_t)c0 * HWSZ + y * WW + x0;

#define PASS2_CH(OFFB, CH) { \
            float v[3][6]; LOADV(OFFB, v) \
            float o[4] = { 0.f, 0.f, 0.f, 0.f }; acc_pass2(v, w, o); \
            float4 ov = { o[0], o[1], o[2], o[3] }; \
            *reinterpret_cast<float4*>(outp + (CH) * HWSZ) = ov; }

        // k=8: sim-store still in flight -> vmcnt(5)
        { const int qo = (po == 0) ? 2 : po - 1;
          WAITB(5)
          PASS2_CH(po * 16384, 0) PASS2_CH(po * 16384 + 8192, 1)
          STAGE2(qo * 16384, 4)
          ROT3(po) }
#pragma unroll 1
        for (int k = 9; k < 14; ++k) {     // channels 2..11, stage 22..31
            const int qo = (po == 0) ? 2 : po - 1;
            WAITB(6)
            const int ch = 2 * (k - 8);
            PASS2_CH(po * 16384, ch) PASS2_CH(po * 16384 + 8192, ch + 1)
            STAGE2(qo * 16384, (2 * k + 4) & 15)
            ROT3(po)
        }
        // k=14: channels 12,13 (no stage)
        { WAITB(6)
          PASS2_CH(po * 16384, 12) PASS2_CH(po * 16384 + 8192, 13)
          ROT3(po) }
        // k=15: channels 14,15
        { WAITB(2)
          PASS2_CH(po * 16384, 14) PASS2_CH(po * 16384 + 8192, 15) }
#undef PASS2_CH
    }
}

template <bool COMPUTE_NEXT>
__global__ __launch_bounds__(256, 3) void step_kernel(const float* __restrict__ F,
                                                      float* __restrict__ Fn,
                                                      float* __restrict__ simout)
{
    // Bijective XCD remap: 1024 blocks, each XCD owns one image.
    const int linear = blockIdx.y * (HH / 2) + blockIdx.x;   // 0..1023
    const int remap  = (linear & 7) * 128 + (linear >> 3);
    const int b      = remap >> 7;
    const int rowblk = remap & 127;

    // 48 KB: 3 pairs x 2 slots x [half2][row4][256 cols] floats.
    __shared__ float4 slab4[3072];

    if (rowblk != 0 && rowblk != 127)      // block-uniform branch, no divergence
        step_body<false, COMPUTE_NEXT>(F, Fn, simout, (char*)slab4, b, rowblk, threadIdx.x);
    else
        step_body<true,  COMPUTE_NEXT>(F, Fn, simout, (char*)slab4, b, rowblk, threadIdx.x);
}

// out[g][t][p] = 0.25 * sum_{i<4} sims[tt][4g+i][p], tt = {0,0,1,2}[t]
__global__ __launch_bounds__(256) void reduce_kernel(const float* __restrict__ sims,
                                                     float* __restrict__ out)
{
    const int idx = blockIdx.x * blockDim.x + threadIdx.x;  // 131072 float4s
    const int p4 = idx & (HWSZ / 4 - 1);
    const int t  = (idx >> 14) & 3;
    const int g  = idx >> 16;
    const int tt = (t <= 1) ? 0 : (t - 1);
    const float4* s = reinterpret_cast<const float4*>(sims) +
                      (size_t)(tt * NIMG + g * 4) * (HWSZ / 4) + p4;
    float4 a = s[0];
    float4 b = s[HWSZ / 4];
    float4 c = s[2 * (HWSZ / 4)];
    float4 d = s[3 * (HWSZ / 4)];
    float4 o;
    o.x = 0.25f * (a.x + b.x + c.x + d.x);
    o.y = 0.25f * (a.y + b.y + c.y + d.y);
    o.z = 0.25f * (a.z + b.z + c.z + d.z);
    o.w = 0.25f * (a.w + b.w + c.w + d.w);
    reinterpret_cast<float4*>(out)[idx] = o;
}

extern "C" void kernel_launch(void* const* d_in, const int* in_sizes, int n_in,
                              void* d_out, int out_size, void* d_ws, size_t ws_size,
                              hipStream_t stream)
{
    const float* F0 = (const float*)d_in[0];
    float* F1   = (float*)d_ws;                       // 64 MB
    float* F2   = F1 + (size_t)NIMG * IMGSZ;          // 64 MB
    float* sims = F2 + (size_t)NIMG * IMGSZ;          // 6 MB

    dim3 block(256);
    dim3 grid(HH / 2, NIMG);

    hipLaunchKernelGGL((step_kernel<true>),  grid, block, 0, stream, F0, F1, sims);
    hipLaunchKernelGGL((step_kernel<true>),  grid, block, 0, stream, F1, F2, sims + (size_t)NIMG * HWSZ);
    hipLaunchKernelGGL((step_kernel<false>), grid, block, 0, stream, F2, nullptr, sims + (size_t)2 * NIMG * HWSZ);

    hipLaunchKernelGGL(reduce_kernel, dim3((2 * 4 * HWSZ / 4) / 256), block, 0, stream,
                       sims, (float*)d_out);
}

// Round 16
// 106.017 us; speedup vs baseline: 1.0262x; 1.0262x over previous
//
#include <hip/hip_runtime.h>

#define HH 256
#define WW 256
#define CC 32
#define HWSZ (HH * WW)
#define IMGSZ (CC * HWSZ)
#define NIMG 8
#define EPSV 1e-8f
#define NCH (CC / 2)   // channels per lane (2-way channel split)

__device__ __forceinline__ void acc_pass1(const float v[3][6],
                                          float sq[3][6], float dotv[8][4])
{
#pragma unroll
    for (int r = 0; r < 3; ++r)
#pragma unroll
        for (int j = 0; j < 6; ++j) sq[r][j] = fmaf(v[r][j], v[r][j], sq[r][j]);
    int d = 0;
#pragma unroll
    for (int dyi = 0; dyi < 3; ++dyi)
#pragma unroll
        for (int dxi = 0; dxi < 3; ++dxi) {
            if (dyi == 1 && dxi == 1) continue;
#pragma unroll
            for (int i = 0; i < 4; ++i)
                dotv[d][i] = fmaf(v[1][i + 1], v[dyi][i + dxi], dotv[d][i]);
            ++d;
        }
}

__device__ __forceinline__ void acc_pass2(const float v[3][6],
                                          const float w[8][4], float o[4])
{
    int d = 0;
#pragma unroll
    for (int dyi = 0; dyi < 3; ++dyi)
#pragma unroll
        for (int dxi = 0; dxi < 3; ++dxi) {
            if (dyi == 1 && dxi == 1) continue;
#pragma unroll
            for (int i = 0; i < 4; ++i)
                o[i] = fmaf(w[d][i], v[dyi][i + dxi], o[i]);
            ++d;
        }
}

// DPP row shifts (16-lane rows). row_shr:1 = lane i <- lane i-1 (shfl_up);
// row_shl:1 = lane i <- lane i+1 (shfl_down). Boundary lanes keep `old`
// (bound_ctrl=false), which we pre-load with the LDS halo value.
__device__ __forceinline__ float dpp_up1(float oldv, float src)
{
    return __int_as_float(__builtin_amdgcn_update_dpp(
        __float_as_int(oldv), __float_as_int(src), 0x111, 0xf, 0xf, false));
}
__device__ __forceinline__ float dpp_dn1(float oldv, float src)
{
    return __int_as_float(__builtin_amdgcn_update_dpp(
        __float_as_int(oldv), __float_as_int(src), 0x101, 0xf, 0xf, false));
}

// Async global -> LDS, 16 B per lane. LDS dest is wave-uniform (HW adds
// lane*16); global source is per-lane.
__device__ __forceinline__ void gload16(const void* g, void* l)
{
    __builtin_amdgcn_global_load_lds(
        (const __attribute__((address_space(1))) void*)g,
        (__attribute__((address_space(3))) void*)l, 16, 0, 0);
}

// Stage slot SLOT: channel (SLOT&15) for half 0 and +16 for half 1 into slab
// buffer (SLOT&3). Each wave stages slab row `wave` (image row clamp(y0-1+wave)).
#define STAGE(SLOT) { \
    const int ch_ = (SLOT) & 15; \
    const int bo_ = ((SLOT) & 3) * 8192; \
    gload16(gsrc0 + (size_t)ch_ * HWSZ,        ldst0 + bo_); \
    gload16(gsrc0 + (size_t)(ch_ + 16) * HWSZ, ldst0 + bo_ + 4096); }

// Counted-vmcnt wait + raw barrier (NOT __syncthreads: that drains vmcnt(0)
// and kills the pipeline). vmcnt(4) keeps the 2 newer stage slots in flight.
#define WAITB(VM) { asm volatile("s_waitcnt vmcnt(" #VM ")" ::: "memory"); \
                    __builtin_amdgcn_s_barrier(); }

// Read this lane's 3x6 window from slab buffer (G&3). b128 at 16B stride
// (conflict-free); x-halo via DPP row-shift with the 16-lane-row boundary
// lanes patched from a b32 LDS read (dummy conflict-free addr elsewhere).
#define LOADV(G, VV) { \
    const char* sp_ = slabb + ((G) & 3) * 8192; \
    _Pragma("unroll") \
    for (int r_ = 0; r_ < 3; ++r_) { \
        float4 m_ = *(const float4*)(sp_ + bM + r_ * 1024); \
        float eL_ = *(const float*)(sp_ + bL2 + r_ * 1024); \
        float eR_ = *(const float*)(sp_ + bR2 + r_ * 1024); \
        const float lu_ = dpp_up1(eL_, m_.w); \
        const float rd_ = dpp_dn1(eR_, m_.x); \
        const bool ok_ = rowok[r_]; \
        VV[r_][0] = (ok_ && xl) ? lu_ : 0.f; \
        VV[r_][1] = ok_ ? m_.x : 0.f; \
        VV[r_][2] = ok_ ? m_.y : 0.f; \
        VV[r_][3] = ok_ ? m_.z : 0.f; \
        VV[r_][4] = ok_ ? m_.w : 0.f; \
        VV[r_][5] = (ok_ && xr) ? rd_ : 0.f; \
    } }

// Lane mapping: half = lane>>5 (16 channels each), tx = lane&31 (4 px each).
// Wave = 128 px (half row); block = 4 waves = 2 rows. All window data is
// LDS-staged via the counted-vmcnt async pipeline. YEDGE=false (interior,
// 98.4% of blocks) folds all row-mask selects away.
template <bool YEDGE, bool COMPUTE_NEXT>
__device__ __forceinline__ void step_body(const float* __restrict__ F,
                                          float* __restrict__ Fn,
                                          float* __restrict__ simout,
                                          char* slabb, int b, int rowblk, int tid)
{
    const int wave = tid >> 6;
    const int lane = tid & 63;
    const int half = lane >> 5;            // channel half
    const int tx   = lane & 31;            // px group
    const int y0   = rowblk * 2;
    const int y    = y0 + (wave >> 1);
    const int x0   = (wave & 1) * 128 + (tx << 2);
    const int c0   = half * NCH;

    const bool ym = YEDGE ? (y > 0) : true;
    const bool yp = YEDGE ? (y < HH - 1) : true;
    const bool xl = x0 > 0, xr = x0 < WW - 4;
    const bool rowok[3] = { ym, true, yp };
    const bool colok[6] = { xl, true, true, true, true, xr };

    const float* Fb = F + (size_t)b * IMGSZ;

    // Staging invariants: this wave stages slab row `wave` = image row clamp(y0-1+wave).
    int arow = y0 - 1 + wave;
    if (YEDGE) arow = arow < 0 ? 0 : (arow > HH - 1 ? HH - 1 : arow);
    const float* gsrc0 = Fb + arow * WW + (lane << 2);
    char* ldst0 = slabb + wave * 1024;     // wave-uniform; +buf/half offsets in STAGE

    // ds-read invariants: rows (wave>>1)+{0,1,2} of own half.
    const int rbase = half * 4096 + (wave >> 1) * 1024;
    const int bM = rbase + x0 * 4;
    // Halo-read addresses (precomputed once): boundary lanes of each 16-lane
    // DPP row read their halo col (clamped at image edge); other lanes read a
    // conflict-free dummy (stride-4B by lane -> 2-way max, free).
    const bool lb = (lane & 15) == 0;
    const bool rb = (lane & 15) == 15;
    const int dummy = rbase + lane * 4;
    const int bL2 = lb ? (rbase + (xl ? x0 * 4 - 4  : 0))    : dummy;
    const int bR2 = rb ? (rbase + (xr ? x0 * 4 + 16 : 1020)) : dummy;

    // ---------------- Pass 1: partial norms + dots over 16 channels ----------
    float sq[3][6];
    float dotv[8][4];
#pragma unroll
    for (int r = 0; r < 3; ++r)
#pragma unroll
        for (int j = 0; j < 6; ++j) sq[r][j] = 0.f;
#pragma unroll
    for (int d = 0; d < 8; ++d)
#pragma unroll
        for (int i = 0; i < 4; ++i) dotv[d][i] = 0.f;

    STAGE(0) STAGE(1) STAGE(2)

#pragma unroll 1
    for (int g = 0; g < (COMPUTE_NEXT ? 16 : 13); ++g) {
        WAITB(4)
        STAGE(g + 3)                       // pass-1 tail slots 16..18 prefetch pass 2
        float v[3][6];
        LOADV(g, v)
        acc_pass1(v, sq, dotv);
    }
    if (!COMPUTE_NEXT) {                   // peeled tail, no further staging
        { WAITB(4) float v[3][6]; LOADV(13, v) acc_pass1(v, sq, dotv); }
        { WAITB(2) float v[3][6]; LOADV(14, v) acc_pass1(v, sq, dotv); }
        { WAITB(0) float v[3][6]; LOADV(15, v) acc_pass1(v, sq, dotv); }
    }

    // Merge the two channel halves (lane bit 5).
#pragma unroll
    for (int r = 0; r < 3; ++r)
#pragma unroll
        for (int j = 0; j < 6; ++j) sq[r][j] += __shfl_xor(sq[r][j], 32);
#pragma unroll
    for (int d = 0; d < 8; ++d)
#pragma unroll
        for (int i = 0; i < 4; ++i) dotv[d][i] += __shfl_xor(dotv[d][i], 32);

    float nrm[3][6];
#pragma unroll
    for (int r = 0; r < 3; ++r)
#pragma unroll
        for (int j = 0; j < 6; ++j) nrm[r][j] = __builtin_amdgcn_sqrtf(sq[r][j]);

    float w[8][4];
    float simarr[4];
#pragma unroll
    for (int i = 0; i < 4; ++i) {
        float s[8];
        const float cn = nrm[1][i + 1];
        float tot = 0.f, cnt = 0.f;
        int d = 0;
#pragma unroll
        for (int dyi = 0; dyi < 3; ++dyi)
#pragma unroll
            for (int dxi = 0; dxi < 3; ++dxi) {
                if (dyi == 1 && dxi == 1) continue;
                const bool m = rowok[dyi] && colok[i + dxi];
                const float den = fmaxf(cn * nrm[dyi][i + dxi], EPSV);
                const float cs = dotv[d][i] * __builtin_amdgcn_rcpf(den);
                s[d] = m ? cs : 0.f;
                tot += s[d];
                cnt += m ? 1.f : 0.f;
                ++d;
            }
        simarr[i] = tot * __builtin_amdgcn_rcpf(cnt);
        if (COMPUTE_NEXT) {
            float mx = s[0];
#pragma unroll
            for (int d2 = 1; d2 < 8; ++d2) mx = fmaxf(mx, s[d2]);
            float wsum = 0.f;
#pragma unroll
            for (int d2 = 0; d2 < 8; ++d2) { w[d2][i] = __expf(s[d2] - mx); wsum += w[d2][i]; }
            const float inv = __builtin_amdgcn_rcpf(wsum);
#pragma unroll
            for (int d2 = 0; d2 < 8; ++d2) w[d2][i] *= inv;
        }
    }
    if (half == 0) {
        float4 simv = { simarr[0], simarr[1], simarr[2], simarr[3] };
        *reinterpret_cast<float4*>(simout + b * HWSZ + y * WW + x0) = simv;
    }

    // ---------------- Pass 2: weighted neighbor average (own 16 channels) ----
    if (COMPUTE_NEXT) {
        float* outp = Fn + (size_t)b * IMGSZ + (size_t)c0 * HWSZ + y * WW + x0;
#pragma unroll 1
        for (int g = 16; g < 29; ++g) {
            WAITB(4)
            STAGE(g + 3)
            float v[3][6];
            LOADV(g, v)
            float o[4] = { 0.f, 0.f, 0.f, 0.f };
            acc_pass2(v, w, o);
            float4 ov = { o[0], o[1], o[2], o[3] };
            *reinterpret_cast<float4*>(outp + (g & 15) * HWSZ) = ov;
        }
        { WAITB(4) float v[3][6]; LOADV(29, v)
          float o[4] = { 0.f, 0.f, 0.f, 0.f }; acc_pass2(v, w, o);
          float4 ov = { o[0], o[1], o[2], o[3] };
          *reinterpret_cast<float4*>(outp + 13 * HWSZ) = ov; }
        { WAITB(2) float v[3][6]; LOADV(30, v)
          float o[4] = { 0.f, 0.f, 0.f, 0.f }; acc_pass2(v, w, o);
          float4 ov = { o[0], o[1], o[2], o[3] };
          *reinterpret_cast<float4*>(outp + 14 * HWSZ) = ov; }
        { WAITB(0) float v[3][6]; LOADV(31, v)
          float o[4] = { 0.f, 0.f, 0.f, 0.f }; acc_pass2(v, w, o);
          float4 ov = { o[0], o[1], o[2], o[3] };
          *reinterpret_cast<float4*>(outp + 15 * HWSZ) = ov; }
    }
}

template <bool COMPUTE_NEXT>
__global__ __launch_bounds__(256, 4) void step_kernel(const float* __restrict__ F,
                                                      float* __restrict__ Fn,
                                                      float* __restrict__ simout)
{
    // Bijective XCD remap: 1024 blocks, each XCD owns one image.
    const int linear = blockIdx.y * (HH / 2) + blockIdx.x;   // 0..1023
    const int remap  = (linear & 7) * 128 + (linear >> 3);
    const int b      = remap >> 7;
    const int rowblk = remap & 127;

    // 32 KB: [buf4][half2][row4][256 cols] floats.
    __shared__ float4 slab4[2048];

    if (rowblk != 0 && rowblk != 127)      // block-uniform branch, no divergence
        step_body<false, COMPUTE_NEXT>(F, Fn, simout, (char*)slab4, b, rowblk, threadIdx.x);
    else
        step_body<true,  COMPUTE_NEXT>(F, Fn, simout, (char*)slab4, b, rowblk, threadIdx.x);
}

// out[g][t][p] = 0.25 * sum_{i<4} sims[tt][4g+i][p], tt = {0,0,1,2}[t]
__global__ __launch_bounds__(256) void reduce_kernel(const float* __restrict__ sims,
                                                     float* __restrict__ out)
{
    const int idx = blockIdx.x * blockDim.x + threadIdx.x;  // 131072 float4s
    const int p4 = idx & (HWSZ / 4 - 1);
    const int t  = (idx >> 14) & 3;
    const int g  = idx >> 16;
    const int tt = (t <= 1) ? 0 : (t - 1);
    const float4* s = reinterpret_cast<const float4*>(sims) +
                      (size_t)(tt * NIMG + g * 4) * (HWSZ / 4) + p4;
    float4 a = s[0];
    float4 b = s[HWSZ / 4];
    float4 c = s[2 * (HWSZ / 4)];
    float4 d = s[3 * (HWSZ / 4)];
    float4 o;
    o.x = 0.25f * (a.x + b.x + c.x + d.x);
    o.y = 0.25f * (a.y + b.y + c.y + d.y);
    o.z = 0.25f * (a.z + b.z + c.z + d.z);
    o.w = 0.25f * (a.w + b.w + c.w + d.w);
    reinterpret_cast<float4*>(out)[idx] = o;
}

extern "C" void kernel_launch(void* const* d_in, const int* in_sizes, int n_in,
                              void* d_out, int out_size, void* d_ws, size_t ws_size,
                              hipStream_t stream)
{
    const float* F0 = (const float*)d_in[0];
    float* F1   = (float*)d_ws;                       // 64 MB
    float* F2   = F1 + (size_t)NIMG * IMGSZ;          // 64 MB
    float* sims = F2 + (size_t)NIMG * IMGSZ;          // 6 MB

    dim3 block(256);
    dim3 grid(HH / 2, NIMG);

    hipLaunchKernelGGL((step_kernel<true>),  grid, block, 0, stream, F0, F1, sims);
    hipLaunchKernelGGL((step_kernel<true>),  grid, block, 0, stream, F1, F2, sims + (size_t)NIMG * HWSZ);
    hipLaunchKernelGGL((step_kernel<false>), grid, block, 0, stream, F2, nullptr, sims + (size_t)2 * NIMG * HWSZ);

    hipLaunchKernelGGL(reduce_kernel, dim3((2 * 4 * HWSZ / 4) / 256), block, 0, stream,
                       sims, (float*)d_out);
}

// Round 17
// 104.235 us; speedup vs baseline: 1.0437x; 1.0171x over previous
//
#include <hip/hip_runtime.h>

#define HH 256
#define WW 256
#define CC 32
#define HWSZ (HH * WW)
#define IMGSZ (CC * HWSZ)
#define NIMG 8
#define EPSV 1e-8f
#define NCH (CC / 2)   // channels per lane (2-way channel split)

// Trimmed pass-1 accumulators: center squares only (halo squares are
// reconstructed post-merge from neighbor lanes), W/E dots shared via ew[].
// dirs: 0=NW 1=N 2=NE 3=SW 4=S 5=SE.
__device__ __forceinline__ void acc_pass1(const float v[3][6],
                                          float sqc[3][4], float dirs[6][4],
                                          float ew[5])
{
#pragma unroll
    for (int r = 0; r < 3; ++r)
#pragma unroll
        for (int j = 0; j < 4; ++j)
            sqc[r][j] = fmaf(v[r][j + 1], v[r][j + 1], sqc[r][j]);
#pragma unroll
    for (int i = 0; i < 4; ++i) {
        const float c = v[1][i + 1];
        dirs[0][i] = fmaf(c, v[0][i],     dirs[0][i]);
        dirs[1][i] = fmaf(c, v[0][i + 1], dirs[1][i]);
        dirs[2][i] = fmaf(c, v[0][i + 2], dirs[2][i]);
        dirs[3][i] = fmaf(c, v[2][i],     dirs[3][i]);
        dirs[4][i] = fmaf(c, v[2][i + 1], dirs[4][i]);
        dirs[5][i] = fmaf(c, v[2][i + 2], dirs[5][i]);
    }
#pragma unroll
    for (int j = 0; j < 5; ++j) ew[j] = fmaf(v[1][j], v[1][j + 1], ew[j]);
}

__device__ __forceinline__ void acc_pass2(const float v[3][6],
                                          const float w[8][4], float o[4])
{
    int d = 0;
#pragma unroll
    for (int dyi = 0; dyi < 3; ++dyi)
#pragma unroll
        for (int dxi = 0; dxi < 3; ++dxi) {
            if (dyi == 1 && dxi == 1) continue;
#pragma unroll
            for (int i = 0; i < 4; ++i)
                o[i] = fmaf(w[d][i], v[dyi][i + dxi], o[i]);
            ++d;
        }
}

// Async global -> LDS, 16 B per lane. LDS dest is wave-uniform (HW adds
// lane*16); global source is per-lane.
__device__ __forceinline__ void gload16(const void* g, void* l)
{
    __builtin_amdgcn_global_load_lds(
        (const __attribute__((address_space(1))) void*)g,
        (__attribute__((address_space(3))) void*)l, 16, 0, 0);
}

// Stage slot SLOT: channel (SLOT&15) for half 0 and +16 for half 1 into slab
// buffer (SLOT&3). Each wave stages slab row `wave` (image row clamp(y0-1+wave)).
#define STAGE(SLOT) { \
    const int ch_ = (SLOT) & 15; \
    const int bo_ = ((SLOT) & 3) * 8192; \
    gload16(gsrc0 + (size_t)ch_ * HWSZ,        ldst0 + bo_); \
    gload16(gsrc0 + (size_t)(ch_ + 16) * HWSZ, ldst0 + bo_ + 4096); }

// Counted-vmcnt wait + raw barrier (NOT __syncthreads: that drains vmcnt(0)
// and kills the pipeline). vmcnt(4) keeps the 2 newer stage slots in flight.
#define WAITB(VM) { asm volatile("s_waitcnt vmcnt(" #VM ")" ::: "memory"); \
                    __builtin_amdgcn_s_barrier(); }

// Read this lane's 3x6 window from slab buffer (G&3). b128 at clean 16B
// stride per 32-lane half (conflict-free); x-halo via distance-1 shuffles;
// LDS scalar only on the 4 edge lanes (predicated).
#define LOADV(G, VV) { \
    const char* sp_ = slabb + ((G) & 3) * 8192; \
    _Pragma("unroll") \
    for (int r_ = 0; r_ < 3; ++r_) { \
        float4 m_ = *(const float4*)(sp_ + bM + r_ * 1024); \
        float e_ = 0.f; \
        if (edge) e_ = *(const float*)(sp_ + bE + r_ * 1024); \
        const float lu_ = __shfl_up(m_.w, 1); \
        const float rd_ = __shfl_down(m_.x, 1); \
        const bool ok_ = rowok[r_]; \
        VV[r_][0] = (ok_ && xl) ? ((tx == 0)  ? e_ : lu_) : 0.f; \
        VV[r_][1] = ok_ ? m_.x : 0.f; \
        VV[r_][2] = ok_ ? m_.y : 0.f; \
        VV[r_][3] = ok_ ? m_.z : 0.f; \
        VV[r_][4] = ok_ ? m_.w : 0.f; \
        VV[r_][5] = (ok_ && xr) ? ((tx == 31) ? e_ : rd_) : 0.f; \
    } }

// Lane mapping: half = lane>>5 (16 channels each), tx = lane&31 (4 px each).
// Wave = 128 px (half row); block = 4 waves = 2 rows. All window data is
// LDS-staged via the counted-vmcnt async pipeline. YEDGE=false (interior,
// 98.4% of blocks) folds all row-mask selects away.
template <bool YEDGE, bool COMPUTE_NEXT>
__device__ __forceinline__ void step_body(const float* __restrict__ F,
                                          float* __restrict__ Fn,
                                          float* __restrict__ simout,
                                          char* slabb, float* exch,
                                          int b, int rowblk, int tid)
{
    const int wave = tid >> 6;
    const int lane = tid & 63;
    const int half = lane >> 5;            // channel half
    const int tx   = lane & 31;            // px group
    const int y0   = rowblk * 2;
    const int y    = y0 + (wave >> 1);
    const int x0   = (wave & 1) * 128 + (tx << 2);
    const int c0   = half * NCH;

    const bool ym = YEDGE ? (y > 0) : true;
    const bool yp = YEDGE ? (y < HH - 1) : true;
    const bool xl = x0 > 0, xr = x0 < WW - 4;
    const bool rowok[3] = { ym, true, yp };
    const bool colok[6] = { xl, true, true, true, true, xr };

    const float* Fb = F + (size_t)b * IMGSZ;

    // Staging invariants: this wave stages slab row `wave` = image row clamp(y0-1+wave).
    int arow = y0 - 1 + wave;
    if (YEDGE) arow = arow < 0 ? 0 : (arow > HH - 1 ? HH - 1 : arow);
    const float* gsrc0 = Fb + arow * WW + (lane << 2);
    char* ldst0 = slabb + wave * 1024;     // wave-uniform; +buf/half offsets in STAGE

    // ds-read invariants: rows (wave>>1)+{0,1,2} of own half.
    const int rbase = half * 4096 + (wave >> 1) * 1024;
    const int bM = rbase + x0 * 4;
    const int bL = rbase + (xl ? x0 * 4 - 4 : 0);
    const int bR = rbase + (xr ? x0 * 4 + 16 : 1020);
    const bool edge = (tx == 0) || (tx == 31);
    const int bE = (tx == 31) ? bR : bL;

    // ---------------- Pass 1: partial norms + dots over 16 channels ----------
    float sqc[3][4];
    float dirs[6][4];
    float ew[5];
#pragma unroll
    for (int r = 0; r < 3; ++r)
#pragma unroll
        for (int j = 0; j < 4; ++j) sqc[r][j] = 0.f;
#pragma unroll
    for (int d = 0; d < 6; ++d)
#pragma unroll
        for (int i = 0; i < 4; ++i) dirs[d][i] = 0.f;
#pragma unroll
    for (int j = 0; j < 5; ++j) ew[j] = 0.f;

    STAGE(0) STAGE(1) STAGE(2)

#pragma unroll 1
    for (int g = 0; g < (COMPUTE_NEXT ? 16 : 13); ++g) {
        WAITB(4)
        STAGE(g + 3)                       // pass-1 tail slots 16..18 prefetch pass 2
        float v[3][6];
        LOADV(g, v)
        acc_pass1(v, sqc, dirs, ew);
    }
    if (!COMPUTE_NEXT) {                   // peeled tail, no further staging
        { WAITB(4) float v[3][6]; LOADV(13, v) acc_pass1(v, sqc, dirs, ew); }
        { WAITB(2) float v[3][6]; LOADV(14, v) acc_pass1(v, sqc, dirs, ew); }
        { WAITB(0) float v[3][6]; LOADV(15, v) acc_pass1(v, sqc, dirs, ew); }
    }

    // Merge the two channel halves (lane bit 5).
#pragma unroll
    for (int r = 0; r < 3; ++r)
#pragma unroll
        for (int j = 0; j < 4; ++j) sqc[r][j] += __shfl_xor(sqc[r][j], 32);
#pragma unroll
    for (int d = 0; d < 6; ++d)
#pragma unroll
        for (int i = 0; i < 4; ++i) dirs[d][i] += __shfl_xor(dirs[d][i], 32);
#pragma unroll
    for (int j = 0; j < 5; ++j) ew[j] += __shfl_xor(ew[j], 32);

    // Reconstruct halo square-sums from neighbor lanes (bitwise-identical
    // values). Interior wave boundary (cols 127/128) goes through a tiny
    // LDS exchange; image-edge lanes are mask-covered in the epilogue.
    if (half == 0 && tx == ((wave & 1) ? 0 : 31)) {
#pragma unroll
        for (int r = 0; r < 3; ++r)
            exch[(wave >> 1) * 6 + (wave & 1) * 3 + r] =
                (wave & 1) ? sqc[r][0] : sqc[r][3];
    }
    asm volatile("s_waitcnt lgkmcnt(0)" ::: "memory");
    __builtin_amdgcn_s_barrier();

    float sqh0[3], sqh5[3];
#pragma unroll
    for (int r = 0; r < 3; ++r) {
        sqh0[r] = __shfl_up(sqc[r][3], 1);
        sqh5[r] = __shfl_down(sqc[r][0], 1);
    }
    if (tx == 31 && (wave & 1) == 0) {
#pragma unroll
        for (int r = 0; r < 3; ++r) sqh5[r] = exch[(wave >> 1) * 6 + 3 + r];
    }
    if (tx == 0 && (wave & 1) == 1) {
#pragma unroll
        for (int r = 0; r < 3; ++r) sqh0[r] = exch[(wave >> 1) * 6 + r];
    }

    float nrm[3][6];
#pragma unroll
    for (int r = 0; r < 3; ++r) {
        nrm[r][0] = __builtin_amdgcn_sqrtf(sqh0[r]);
#pragma unroll
        for (int j = 0; j < 4; ++j) nrm[r][j + 1] = __builtin_amdgcn_sqrtf(sqc[r][j]);
        nrm[r][5] = __builtin_amdgcn_sqrtf(sqh5[r]);
    }

    float w[8][4];
    float simarr[4];
#pragma unroll
    for (int i = 0; i < 4; ++i) {
        const float num[8] = { dirs[0][i], dirs[1][i], dirs[2][i],
                               ew[i], ew[i + 1],
                               dirs[3][i], dirs[4][i], dirs[5][i] };
        float s[8];
        const float cn = nrm[1][i + 1];
        float tot = 0.f, cnt = 0.f;
        int d = 0;
#pragma unroll
        for (int dyi = 0; dyi < 3; ++dyi)
#pragma unroll
            for (int dxi = 0; dxi < 3; ++dxi) {
                if (dyi == 1 && dxi == 1) continue;
                const bool m = rowok[dyi] && colok[i + dxi];
                const float den = fmaxf(cn * nrm[dyi][i + dxi], EPSV);
                const float cs = num[d] * __builtin_amdgcn_rcpf(den);
                s[d] = m ? cs : 0.f;
                tot += s[d];
                cnt += m ? 1.f : 0.f;
                ++d;
            }
        simarr[i] = tot * __builtin_amdgcn_rcpf(cnt);
        if (COMPUTE_NEXT) {
            float mx = s[0];
#pragma unroll
            for (int d2 = 1; d2 < 8; ++d2) mx = fmaxf(mx, s[d2]);
            float wsum = 0.f;
#pragma unroll
            for (int d2 = 0; d2 < 8; ++d2) { w[d2][i] = __expf(s[d2] - mx); wsum += w[d2][i]; }
            const float inv = __builtin_amdgcn_rcpf(wsum);
#pragma unroll
            for (int d2 = 0; d2 < 8; ++d2) w[d2][i] *= inv;
        }
    }
    if (half == 0) {
        float4 simv = { simarr[0], simarr[1], simarr[2], simarr[3] };
        *reinterpret_cast<float4*>(simout + b * HWSZ + y * WW + x0) = simv;
    }

    // ---------------- Pass 2: weighted neighbor average (own 16 channels) ----
    if (COMPUTE_NEXT) {
        float* outp = Fn + (size_t)b * IMGSZ + (size_t)c0 * HWSZ + y * WW + x0;
#pragma unroll 1
        for (int g = 16; g < 29; ++g) {
            WAITB(4)
            STAGE(g + 3)
            float v[3][6];
            LOADV(g, v)
            float o[4] = { 0.f, 0.f, 0.f, 0.f };
            acc_pass2(v, w, o);
            float4 ov = { o[0], o[1], o[2], o[3] };
            *reinterpret_cast<float4*>(outp + (g & 15) * HWSZ) = ov;
        }
        { WAITB(4) float v[3][6]; LOADV(29, v)
          float o[4] = { 0.f, 0.f, 0.f, 0.f }; acc_pass2(v, w, o);
          float4 ov = { o[0], o[1], o[2], o[3] };
          *reinterpret_cast<float4*>(outp + 13 * HWSZ) = ov; }
        { WAITB(2) float v[3][6]; LOADV(30, v)
          float o[4] = { 0.f, 0.f, 0.f, 0.f }; acc_pass2(v, w, o);
          float4 ov = { o[0], o[1], o[2], o[3] };
          *reinterpret_cast<float4*>(outp + 14 * HWSZ) = ov; }
        { WAITB(0) float v[3][6]; LOADV(31, v)
          float o[4] = { 0.f, 0.f, 0.f, 0.f }; acc_pass2(v, w, o);
          float4 ov = { o[0], o[1], o[2], o[3] };
          *reinterpret_cast<float4*>(outp + 15 * HWSZ) = ov; }
    }
}

template <bool COMPUTE_NEXT>
__global__ __launch_bounds__(256, 4) void step_kernel(const float* __restrict__ F,
                                                      float* __restrict__ Fn,
                                                      float* __restrict__ simout)
{
    // Bijective XCD remap: 1024 blocks, each XCD owns one image.
    const int linear = blockIdx.y * (HH / 2) + blockIdx.x;   // 0..1023
    const int remap  = (linear & 7) * 128 + (linear >> 3);
    const int b      = remap >> 7;
    const int rowblk = remap & 127;

    // 32 KB: [buf4][half2][row4][256 cols] floats, + 48 B boundary exchange.
    __shared__ float4 slab4[2048];
    __shared__ float exch[12];

    if (rowblk != 0 && rowblk != 127)      // block-uniform branch, no divergence
        step_body<false, COMPUTE_NEXT>(F, Fn, simout, (char*)slab4, exch, b, rowblk, threadIdx.x);
    else
        step_body<true,  COMPUTE_NEXT>(F, Fn, simout, (char*)slab4, exch, b, rowblk, threadIdx.x);
}

// out[g][t][p] = 0.25 * sum_{i<4} sims[tt][4g+i][p], tt = {0,0,1,2}[t]
__global__ __launch_bounds__(256) void reduce_kernel(const float* __restrict__ sims,
                                                     float* __restrict__ out)
{
    const int idx = blockIdx.x * blockDim.x + threadIdx.x;  // 131072 float4s
    const int p4 = idx & (HWSZ / 4 - 1);
    const int t  = (idx >> 14) & 3;
    const int g  = idx >> 16;
    const int tt = (t <= 1) ? 0 : (t - 1);
    const float4* s = reinterpret_cast<const float4*>(sims) +
                      (size_t)(tt * NIMG + g * 4) * (HWSZ / 4) + p4;
    float4 a = s[0];
    float4 b = s[HWSZ / 4];
    float4 c = s[2 * (HWSZ / 4)];
    float4 d = s[3 * (HWSZ / 4)];
    float4 o;
    o.x = 0.25f * (a.x + b.x + c.x + d.x);
    o.y = 0.25f * (a.y + b.y + c.y + d.y);
    o.z = 0.25f * (a.z + b.z + c.z + d.z);
    o.w = 0.25f * (a.w + b.w + c.w + d.w);
    reinterpret_cast<float4*>(out)[idx] = o;
}

extern "C" void kernel_launch(void* const* d_in, const int* in_sizes, int n_in,
                              void* d_out, int out_size, void* d_ws, size_t ws_size,
                              hipStream_t stream)
{
    const float* F0 = (const float*)d_in[0];
    float* F1   = (float*)d_ws;                       // 64 MB
    float* F2   = F1 + (size_t)NIMG * IMGSZ;          // 64 MB
    float* sims = F2 + (size_t)NIMG * IMGSZ;          // 6 MB

    dim3 block(256);
    dim3 grid(HH / 2, NIMG);

    hipLaunchKernelGGL((step_kernel<true>),  grid, block, 0, stream, F0, F1, sims);
    hipLaunchKernelGGL((step_kernel<true>),  grid, block, 0, stream, F1, F2, sims + (size_t)NIMG * HWSZ);
    hipLaunchKernelGGL((step_kernel<false>), grid, block, 0, stream, F2, nullptr, sims + (size_t)2 * NIMG * HWSZ);

    hipLaunchKernelGGL(reduce_kernel, dim3((2 * 4 * HWSZ / 4) / 256), block, 0, stream,
                       sims, (float*)d_out);
}

// Round 18
// 98.957 us; speedup vs baseline: 1.0994x; 1.0533x over previous
//
#include <hip/hip_runtime.h>
#include <hip/hip_fp16.h>

#define HH 256
#define WW 256
#define CC 32
#define HWSZ (HH * WW)
#define IMGSZ (CC * HWSZ)
#define NIMG 8
#define EPSV 1e-8f
#define NCH (CC / 2)   // channels per lane (2-way channel split)

__device__ __forceinline__ void acc_pass1(const float v[3][6],
                                          float sq[3][6], float dotv[8][4])
{
#pragma unroll
    for (int r = 0; r < 3; ++r)
#pragma unroll
        for (int j = 0; j < 6; ++j) sq[r][j] = fmaf(v[r][j], v[r][j], sq[r][j]);
    int d = 0;
#pragma unroll
    for (int dyi = 0; dyi < 3; ++dyi)
#pragma unroll
        for (int dxi = 0; dxi < 3; ++dxi) {
            if (dyi == 1 && dxi == 1) continue;
#pragma unroll
            for (int i = 0; i < 4; ++i)
                dotv[d][i] = fmaf(v[1][i + 1], v[dyi][i + dxi], dotv[d][i]);
            ++d;
        }
}

__device__ __forceinline__ void acc_pass2(const float v[3][6],
                                          const float w[8][4], float o[4])
{
    int d = 0;
#pragma unroll
    for (int dyi = 0; dyi < 3; ++dyi)
#pragma unroll
        for (int dxi = 0; dxi < 3; ++dxi) {
            if (dyi == 1 && dxi == 1) continue;
#pragma unroll
            for (int i = 0; i < 4; ++i)
                o[i] = fmaf(w[d][i], v[dyi][i + dxi], o[i]);
            ++d;
        }
}

__device__ __forceinline__ void gload16(const void* g, void* l)
{
    __builtin_amdgcn_global_load_lds(
        (const __attribute__((address_space(1))) void*)g,
        (__attribute__((address_space(3))) void*)l, 16, 0, 0);
}

__device__ __forceinline__ float cvtlo(unsigned u)
{ return __half2float(__ushort_as_half((unsigned short)(u & 0xffffu))); }
__device__ __forceinline__ float cvthi(unsigned u)
{ return __half2float(__ushort_as_half((unsigned short)(u >> 16))); }
__device__ __forceinline__ unsigned pkh(float a, float b)
{
    return (unsigned)__half_as_ushort(__float2half_rn(a)) |
           ((unsigned)__half_as_ushort(__float2half_rn(b)) << 16);
}

#define WAITB(VM) { asm volatile("s_waitcnt vmcnt(" #VM ")" ::: "memory"); \
                    __builtin_amdgcn_s_barrier(); }

// ===================== STEP 1: f32 input -> fp16 output =====================
// R13-verbatim pipeline; only the pass-2 store converts to fp16.

#define STAGE(SLOT) { \
    const int ch_ = (SLOT) & 15; \
    const int bo_ = ((SLOT) & 3) * 8192; \
    gload16(gsrc0 + (size_t)ch_ * HWSZ,        ldst0 + bo_); \
    gload16(gsrc0 + (size_t)(ch_ + 16) * HWSZ, ldst0 + bo_ + 4096); }

#define LOADV(G, VV) { \
    const char* sp_ = slabb + ((G) & 3) * 8192; \
    _Pragma("unroll") \
    for (int r_ = 0; r_ < 3; ++r_) { \
        float4 m_ = *(const float4*)(sp_ + bM + r_ * 1024); \
        float e_ = 0.f; \
        if (edge) e_ = *(const float*)(sp_ + bE + r_ * 1024); \
        const float lu_ = __shfl_up(m_.w, 1); \
        const float rd_ = __shfl_down(m_.x, 1); \
        const bool ok_ = rowok[r_]; \
        VV[r_][0] = (ok_ && xl) ? ((tx == 0)  ? e_ : lu_) : 0.f; \
        VV[r_][1] = ok_ ? m_.x : 0.f; \
        VV[r_][2] = ok_ ? m_.y : 0.f; \
        VV[r_][3] = ok_ ? m_.z : 0.f; \
        VV[r_][4] = ok_ ? m_.w : 0.f; \
        VV[r_][5] = (ok_ && xr) ? ((tx == 31) ? e_ : rd_) : 0.f; \
    } }

template <bool YEDGE>
__device__ __forceinline__ void step1_body(const float* __restrict__ F,
                                           unsigned short* __restrict__ Fn,
                                           float* __restrict__ simout,
                                           char* slabb, int b, int rowblk, int tid)
{
    const int wave = tid >> 6;
    const int lane = tid & 63;
    const int half = lane >> 5;
    const int tx   = lane & 31;
    const int y0   = rowblk * 2;
    const int y    = y0 + (wave >> 1);
    const int x0   = (wave & 1) * 128 + (tx << 2);
    const int c0   = half * NCH;

    const bool ym = YEDGE ? (y > 0) : true;
    const bool yp = YEDGE ? (y < HH - 1) : true;
    const bool xl = x0 > 0, xr = x0 < WW - 4;
    const bool rowok[3] = { ym, true, yp };
    const bool colok[6] = { xl, true, true, true, true, xr };

    const float* Fb = F + (size_t)b * IMGSZ;
    int arow = y0 - 1 + wave;
    if (YEDGE) arow = arow < 0 ? 0 : (arow > HH - 1 ? HH - 1 : arow);
    const float* gsrc0 = Fb + arow * WW + (lane << 2);
    char* ldst0 = slabb + wave * 1024;

    const int rbase = half * 4096 + (wave >> 1) * 1024;
    const int bM = rbase + x0 * 4;
    const int bL = rbase + (xl ? x0 * 4 - 4 : 0);
    const int bR = rbase + (xr ? x0 * 4 + 16 : 1020);
    const bool edge = (tx == 0) || (tx == 31);
    const int bE = (tx == 31) ? bR : bL;

    float sq[3][6];
    float dotv[8][4];
#pragma unroll
    for (int r = 0; r < 3; ++r)
#pragma unroll
        for (int j = 0; j < 6; ++j) sq[r][j] = 0.f;
#pragma unroll
    for (int d = 0; d < 8; ++d)
#pragma unroll
        for (int i = 0; i < 4; ++i) dotv[d][i] = 0.f;

    STAGE(0) STAGE(1) STAGE(2)

#pragma unroll 1
    for (int g = 0; g < 16; ++g) {
        WAITB(4)
        STAGE(g + 3)
        float v[3][6];
        LOADV(g, v)
        acc_pass1(v, sq, dotv);
    }

#pragma unroll
    for (int r = 0; r < 3; ++r)
#pragma unroll
        for (int j = 0; j < 6; ++j) sq[r][j] += __shfl_xor(sq[r][j], 32);
#pragma unroll
    for (int d = 0; d < 8; ++d)
#pragma unroll
        for (int i = 0; i < 4; ++i) dotv[d][i] += __shfl_xor(dotv[d][i], 32);

    float nrm[3][6];
#pragma unroll
    for (int r = 0; r < 3; ++r)
#pragma unroll
        for (int j = 0; j < 6; ++j) nrm[r][j] = __builtin_amdgcn_sqrtf(sq[r][j]);

    float w[8][4];
    float simarr[4];
#pragma unroll
    for (int i = 0; i < 4; ++i) {
        float s[8];
        const float cn = nrm[1][i + 1];
        float tot = 0.f, cnt = 0.f;
        int d = 0;
#pragma unroll
        for (int dyi = 0; dyi < 3; ++dyi)
#pragma unroll
            for (int dxi = 0; dxi < 3; ++dxi) {
                if (dyi == 1 && dxi == 1) continue;
                const bool m = rowok[dyi] && colok[i + dxi];
                const float den = fmaxf(cn * nrm[dyi][i + dxi], EPSV);
                const float cs = dotv[d][i] * __builtin_amdgcn_rcpf(den);
                s[d] = m ? cs : 0.f;
                tot += s[d];
                cnt += m ? 1.f : 0.f;
                ++d;
            }
        simarr[i] = tot * __builtin_amdgcn_rcpf(cnt);
        {
            float mx = s[0];
#pragma unroll
            for (int d2 = 1; d2 < 8; ++d2) mx = fmaxf(mx, s[d2]);
            float wsum = 0.f;
#pragma unroll
            for (int d2 = 0; d2 < 8; ++d2) { w[d2][i] = __expf(s[d2] - mx); wsum += w[d2][i]; }
            const float inv = __builtin_amdgcn_rcpf(wsum);
#pragma unroll
            for (int d2 = 0; d2 < 8; ++d2) w[d2][i] *= inv;
        }
    }
    if (half == 0) {
        float4 simv = { simarr[0], simarr[1], simarr[2], simarr[3] };
        *reinterpret_cast<float4*>(simout + b * HWSZ + y * WW + x0) = simv;
    }

    {
        unsigned short* outp = Fn + (size_t)b * IMGSZ + (size_t)c0 * HWSZ + y * WW + x0;
#pragma unroll 1
        for (int g = 16; g < 29; ++g) {
            WAITB(4)
            STAGE(g + 3)
            float v[3][6];
            LOADV(g, v)
            float o[4] = { 0.f, 0.f, 0.f, 0.f };
            acc_pass2(v, w, o);
            uint2 ov; ov.x = pkh(o[0], o[1]); ov.y = pkh(o[2], o[3]);
            *reinterpret_cast<uint2*>(outp + (g & 15) * HWSZ) = ov;
        }
        { WAITB(4) float v[3][6]; LOADV(29, v)
          float o[4] = { 0.f, 0.f, 0.f, 0.f }; acc_pass2(v, w, o);
          uint2 ov; ov.x = pkh(o[0], o[1]); ov.y = pkh(o[2], o[3]);
          *reinterpret_cast<uint2*>(outp + 13 * HWSZ) = ov; }
        { WAITB(2) float v[3][6]; LOADV(30, v)
          float o[4] = { 0.f, 0.f, 0.f, 0.f }; acc_pass2(v, w, o);
          uint2 ov; ov.x = pkh(o[0], o[1]); ov.y = pkh(o[2], o[3]);
          *reinterpret_cast<uint2*>(outp + 14 * HWSZ) = ov; }
        { WAITB(0) float v[3][6]; LOADV(31, v)
          float o[4] = { 0.f, 0.f, 0.f, 0.f }; acc_pass2(v, w, o);
          uint2 ov; ov.x = pkh(o[0], o[1]); ov.y = pkh(o[2], o[3]);
          *reinterpret_cast<uint2*>(outp + 15 * HWSZ) = ov; }
    }
}

__global__ __launch_bounds__(256, 4) void step1_kernel(const float* __restrict__ F,
                                                       unsigned short* __restrict__ Fn,
                                                       float* __restrict__ simout)
{
    const int linear = blockIdx.y * (HH / 2) + blockIdx.x;
    const int remap  = (linear & 7) * 128 + (linear >> 3);
    const int b      = remap >> 7;
    const int rowblk = remap & 127;

    __shared__ float4 slab4[2048];   // 32 KB

    if (rowblk != 0 && rowblk != 127)
        step1_body<false>(F, Fn, simout, (char*)slab4, b, rowblk, threadIdx.x);
    else
        step1_body<true>(F, Fn, simout, (char*)slab4, b, rowblk, threadIdx.x);
}

// ===================== STEPS 2,3: fp16 input =====================
// Slab slot = [half2][row4][256 fp16] = 4 KB; 4 slots = 16 KB.
// Each wave stages one 2-row pair (1 KB) per slot: 1 gload16/wave/slot.

#define STAGE_H(SLOT) { \
    gload16(gsrcH + (size_t)(((SLOT) & 15) + halfS * 16) * HWSZ, \
            ldstH + ((SLOT) & 3) * 4096); }

#define LOADV_H(G, VV) { \
    const char* sp_ = slabb + ((G) & 3) * 4096; \
    _Pragma("unroll") \
    for (int r_ = 0; r_ < 3; ++r_) { \
        uint2 b_ = *(const uint2*)(sp_ + bMH + r_ * 512); \
        float e_ = 0.f; \
        if (edge && eok) { \
            unsigned eu_ = *(const unsigned*)(sp_ + bEH + r_ * 512); \
            e_ = (tx == 31) ? cvtlo(eu_) : cvthi(eu_); \
        } \
        const unsigned lu32_ = __shfl_up(b_.y, 1); \
        const unsigned rd32_ = __shfl_down(b_.x, 1); \
        const bool ok_ = rowok[r_]; \
        VV[r_][0] = (ok_ && xl) ? ((tx == 0)  ? e_ : cvthi(lu32_)) : 0.f; \
        VV[r_][1] = ok_ ? cvtlo(b_.x) : 0.f; \
        VV[r_][2] = ok_ ? cvthi(b_.x) : 0.f; \
        VV[r_][3] = ok_ ? cvtlo(b_.y) : 0.f; \
        VV[r_][4] = ok_ ? cvthi(b_.y) : 0.f; \
        VV[r_][5] = (ok_ && xr) ? ((tx == 31) ? e_ : cvtlo(rd32_)) : 0.f; \
    } }

template <bool YEDGE, bool COMPUTE_NEXT>
__device__ __forceinline__ void steph_body(const unsigned short* __restrict__ F,
                                           unsigned short* __restrict__ Fn,
                                           float* __restrict__ simout,
                                           char* slabb, int b, int rowblk, int tid)
{
    const int wave = tid >> 6;
    const int lane = tid & 63;
    const int half = lane >> 5;
    const int tx   = lane & 31;
    const int y0   = rowblk * 2;
    const int y    = y0 + (wave >> 1);
    const int x0   = (wave & 1) * 128 + (tx << 2);
    const int c0   = half * NCH;

    const bool ym = YEDGE ? (y > 0) : true;
    const bool yp = YEDGE ? (y < HH - 1) : true;
    const bool xl = x0 > 0, xr = x0 < WW - 4;
    const bool rowok[3] = { ym, true, yp };
    const bool colok[6] = { xl, true, true, true, true, xr };

    const unsigned short* Fb = F + (size_t)b * IMGSZ;

    // Staging role: wave = (halfS, rowpair). One gload16 = 2 fp16 rows (1 KB).
    const int halfS = wave >> 1;
    const int rp    = wave & 1;
    int srow = y0 - 1 + 2 * rp;
    int dsh  = 0;
    if (YEDGE) {
        if (srow < 0)            { srow = 0;      dsh = 512;  }  // rows 0,1 -> slab rows 1,2
        else if (srow + 1 > HH - 1) { srow = HH - 2; dsh = -512; } // rows 254,255 -> slab 1,2
    }
    const unsigned short* gsrcH = Fb + srow * WW + lane * 8;
    char* ldstH = slabb + halfS * 2048 + rp * 1024 + dsh;

    // Consume invariants: rows (wave>>1)+{0,1,2} of own half, 512 B row pitch.
    const int bMH = half * 2048 + (wave >> 1) * 512 + x0 * 2;
    const bool edge = (tx == 0) || (tx == 31);
    const bool eok  = (tx == 31) ? xr : xl;
    const int bEH   = (tx == 31) ? (bMH + 8) : (bMH - 4);

    float sq[3][6];
    float dotv[8][4];
#pragma unroll
    for (int r = 0; r < 3; ++r)
#pragma unroll
        for (int j = 0; j < 6; ++j) sq[r][j] = 0.f;
#pragma unroll
    for (int d = 0; d < 8; ++d)
#pragma unroll
        for (int i = 0; i < 4; ++i) dotv[d][i] = 0.f;

    STAGE_H(0) STAGE_H(1) STAGE_H(2)

#pragma unroll 1
    for (int g = 0; g < (COMPUTE_NEXT ? 16 : 13); ++g) {
        WAITB(2)
        STAGE_H(g + 3)
        float v[3][6];
        LOADV_H(g, v)
        acc_pass1(v, sq, dotv);
    }
    if (!COMPUTE_NEXT) {
        { WAITB(2) float v[3][6]; LOADV_H(13, v) acc_pass1(v, sq, dotv); }
        { WAITB(1) float v[3][6]; LOADV_H(14, v) acc_pass1(v, sq, dotv); }
        { WAITB(0) float v[3][6]; LOADV_H(15, v) acc_pass1(v, sq, dotv); }
    }

#pragma unroll
    for (int r = 0; r < 3; ++r)
#pragma unroll
        for (int j = 0; j < 6; ++j) sq[r][j] += __shfl_xor(sq[r][j], 32);
#pragma unroll
    for (int d = 0; d < 8; ++d)
#pragma unroll
        for (int i = 0; i < 4; ++i) dotv[d][i] += __shfl_xor(dotv[d][i], 32);

    float nrm[3][6];
#pragma unroll
    for (int r = 0; r < 3; ++r)
#pragma unroll
        for (int j = 0; j < 6; ++j) nrm[r][j] = __builtin_amdgcn_sqrtf(sq[r][j]);

    float w[8][4];
    float simarr[4];
#pragma unroll
    for (int i = 0; i < 4; ++i) {
        float s[8];
        const float cn = nrm[1][i + 1];
        float tot = 0.f, cnt = 0.f;
        int d = 0;
#pragma unroll
        for (int dyi = 0; dyi < 3; ++dyi)
#pragma unroll
            for (int dxi = 0; dxi < 3; ++dxi) {
                if (dyi == 1 && dxi == 1) continue;
                const bool m = rowok[dyi] && colok[i + dxi];
                const float den = fmaxf(cn * nrm[dyi][i + dxi], EPSV);
                const float cs = dotv[d][i] * __builtin_amdgcn_rcpf(den);
                s[d] = m ? cs : 0.f;
                tot += s[d];
                cnt += m ? 1.f : 0.f;
                ++d;
            }
        simarr[i] = tot * __builtin_amdgcn_rcpf(cnt);
        if (COMPUTE_NEXT) {
            float mx = s[0];
#pragma unroll
            for (int d2 = 1; d2 < 8; ++d2) mx = fmaxf(mx, s[d2]);
            float wsum = 0.f;
#pragma unroll
            for (int d2 = 0; d2 < 8; ++d2) { w[d2][i] = __expf(s[d2] - mx); wsum += w[d2][i]; }
            const float inv = __builtin_amdgcn_rcpf(wsum);
#pragma unroll
            for (int d2 = 0; d2 < 8; ++d2) w[d2][i] *= inv;
        }
    }
    if (half == 0) {
        float4 simv = { simarr[0], simarr[1], simarr[2], simarr[3] };
        *reinterpret_cast<float4*>(simout + b * HWSZ + y * WW + x0) = simv;
    }

    if (COMPUTE_NEXT) {
        unsigned short* outp = Fn + (size_t)b * IMGSZ + (size_t)c0 * HWSZ + y * WW + x0;

#define PASS2H(VM, G) { \
            WAITB(VM) \
            if ((G) < 29) STAGE_H((G) + 3) \
            float v[3][6]; \
            LOADV_H(G, v) \
            float o[4] = { 0.f, 0.f, 0.f, 0.f }; \
            acc_pass2(v, w, o); \
            uint2 ov; ov.x = pkh(o[0], o[1]); ov.y = pkh(o[2], o[3]); \
            *reinterpret_cast<uint2*>(outp + ((G) & 15) * HWSZ) = ov; }

        PASS2H(3, 16)
        PASS2H(4, 17)
#pragma unroll 1
        for (int g = 18; g < 29; ++g) {
            PASS2H(5, g)
        }
        PASS2H(5, 29)
        PASS2H(4, 30)
        PASS2H(3, 31)
#undef PASS2H
    }
}

template <bool COMPUTE_NEXT>
__global__ __launch_bounds__(256, 4) void steph_kernel(const unsigned short* __restrict__ F,
                                                       unsigned short* __restrict__ Fn,
                                                       float* __restrict__ simout)
{
    const int linear = blockIdx.y * (HH / 2) + blockIdx.x;
    const int remap  = (linear & 7) * 128 + (linear >> 3);
    const int b      = remap >> 7;
    const int rowblk = remap & 127;

    __shared__ float4 slabH[1024];   // 16 KB

    if (rowblk != 0 && rowblk != 127)
        steph_body<false, COMPUTE_NEXT>(F, Fn, simout, (char*)slabH, b, rowblk, threadIdx.x);
    else
        steph_body<true,  COMPUTE_NEXT>(F, Fn, simout, (char*)slabH, b, rowblk, threadIdx.x);
}

// out[g][t][p] = 0.25 * sum_{i<4} sims[tt][4g+i][p], tt = {0,0,1,2}[t]
__global__ __launch_bounds__(256) void reduce_kernel(const float* __restrict__ sims,
                                                     float* __restrict__ out)
{
    const int idx = blockIdx.x * blockDim.x + threadIdx.x;
    const int p4 = idx & (HWSZ / 4 - 1);
    const int t  = (idx >> 14) & 3;
    const int g  = idx >> 16;
    const int tt = (t <= 1) ? 0 : (t - 1);
    const float4* s = reinterpret_cast<const float4*>(sims) +
                      (size_t)(tt * NIMG + g * 4) * (HWSZ / 4) + p4;
    float4 a = s[0];
    float4 b = s[HWSZ / 4];
    float4 c = s[2 * (HWSZ / 4)];
    float4 d = s[3 * (HWSZ / 4)];
    float4 o;
    o.x = 0.25f * (a.x + b.x + c.x + d.x);
    o.y = 0.25f * (a.y + b.y + c.y + d.y);
    o.z = 0.25f * (a.z + b.z + c.z + d.z);
    o.w = 0.25f * (a.w + b.w + c.w + d.w);
    reinterpret_cast<float4*>(out)[idx] = o;
}

extern "C" void kernel_launch(void* const* d_in, const int* in_sizes, int n_in,
                              void* d_out, int out_size, void* d_ws, size_t ws_size,
                              hipStream_t stream)
{
    const float* F0 = (const float*)d_in[0];
    unsigned short* F1h = (unsigned short*)d_ws;                 // 32 MB fp16
    unsigned short* F2h = F1h + (size_t)NIMG * IMGSZ;            // 32 MB fp16
    float* sims = (float*)(F2h + (size_t)NIMG * IMGSZ);          // 6 MB f32

    dim3 block(256);
    dim3 grid(HH / 2, NIMG);

    hipLaunchKernelGGL(step1_kernel,          grid, block, 0, stream, F0, F1h, sims);
    hipLaunchKernelGGL((steph_kernel<true>),  grid, block, 0, stream, F1h, F2h, sims + (size_t)NIMG * HWSZ);
    hipLaunchKernelGGL((steph_kernel<false>), grid, block, 0, stream, F2h, nullptr, sims + (size_t)2 * NIMG * HWSZ);

    hipLaunchKernelGGL(reduce_kernel, dim3((2 * 4 * HWSZ / 4) / 256), block, 0, stream,
                       sims, (float*)d_out);
}

// Round 19
// 96.148 us; speedup vs baseline: 1.1315x; 1.0292x over previous
//
#include <hip/hip_runtime.h>
#include <hip/hip_fp16.h>

#define HH 256
#define WW 256
#define CC 32
#define HWSZ (HH * WW)
#define IMGSZ (CC * HWSZ)
#define NIMG 8
#define EPSV 1e-8f
#define NCH (CC / 2)   // channels per lane (2-way channel split)

__device__ __forceinline__ void acc_pass1(const float v[3][6],
                                          float sq[3][6], float dotv[8][4])
{
#pragma unroll
    for (int r = 0; r < 3; ++r)
#pragma unroll
        for (int j = 0; j < 6; ++j) sq[r][j] = fmaf(v[r][j], v[r][j], sq[r][j]);
    int d = 0;
#pragma unroll
    for (int dyi = 0; dyi < 3; ++dyi)
#pragma unroll
        for (int dxi = 0; dxi < 3; ++dxi) {
            if (dyi == 1 && dxi == 1) continue;
#pragma unroll
            for (int i = 0; i < 4; ++i)
                dotv[d][i] = fmaf(v[1][i + 1], v[dyi][i + dxi], dotv[d][i]);
            ++d;
        }
}

__device__ __forceinline__ void acc_pass2(const float v[3][6],
                                          const float w[8][4], float o[4])
{
    int d = 0;
#pragma unroll
    for (int dyi = 0; dyi < 3; ++dyi)
#pragma unroll
        for (int dxi = 0; dxi < 3; ++dxi) {
            if (dyi == 1 && dxi == 1) continue;
#pragma unroll
            for (int i = 0; i < 4; ++i)
                o[i] = fmaf(w[d][i], v[dyi][i + dxi], o[i]);
            ++d;
        }
}

__device__ __forceinline__ void gload16(const void* g, void* l)
{
    __builtin_amdgcn_global_load_lds(
        (const __attribute__((address_space(1))) void*)g,
        (__attribute__((address_space(3))) void*)l, 16, 0, 0);
}

__device__ __forceinline__ float cvtlo(unsigned u)
{ return __half2float(__ushort_as_half((unsigned short)(u & 0xffffu))); }
__device__ __forceinline__ float cvthi(unsigned u)
{ return __half2float(__ushort_as_half((unsigned short)(u >> 16))); }
__device__ __forceinline__ unsigned pkh(float a, float b)
{
    return (unsigned)__half_as_ushort(__float2half_rn(a)) |
           ((unsigned)__half_as_ushort(__float2half_rn(b)) << 16);
}

#define WAITB(VM) { asm volatile("s_waitcnt vmcnt(" #VM ")" ::: "memory"); \
                    __builtin_amdgcn_s_barrier(); }

// ===================== STEP 1: f32 input -> fp16 output =====================
// R13-verbatim pipeline; only the pass-2 store converts to fp16.

#define STAGE(SLOT) { \
    const int ch_ = (SLOT) & 15; \
    const int bo_ = ((SLOT) & 3) * 8192; \
    gload16(gsrc0 + (size_t)ch_ * HWSZ,        ldst0 + bo_); \
    gload16(gsrc0 + (size_t)(ch_ + 16) * HWSZ, ldst0 + bo_ + 4096); }

#define LOADV(G, VV) { \
    const char* sp_ = slabb + ((G) & 3) * 8192; \
    _Pragma("unroll") \
    for (int r_ = 0; r_ < 3; ++r_) { \
        float4 m_ = *(const float4*)(sp_ + bM + r_ * 1024); \
        float e_ = 0.f; \
        if (edge) e_ = *(const float*)(sp_ + bE + r_ * 1024); \
        const float lu_ = __shfl_up(m_.w, 1); \
        const float rd_ = __shfl_down(m_.x, 1); \
        const bool ok_ = rowok[r_]; \
        VV[r_][0] = (ok_ && xl) ? ((tx == 0)  ? e_ : lu_) : 0.f; \
        VV[r_][1] = ok_ ? m_.x : 0.f; \
        VV[r_][2] = ok_ ? m_.y : 0.f; \
        VV[r_][3] = ok_ ? m_.z : 0.f; \
        VV[r_][4] = ok_ ? m_.w : 0.f; \
        VV[r_][5] = (ok_ && xr) ? ((tx == 31) ? e_ : rd_) : 0.f; \
    } }

template <bool YEDGE>
__device__ __forceinline__ void step1_body(const float* __restrict__ F,
                                           unsigned short* __restrict__ Fn,
                                           float* __restrict__ simout,
                                           char* slabb, int b, int rowblk, int tid)
{
    const int wave = tid >> 6;
    const int lane = tid & 63;
    const int half = lane >> 5;
    const int tx   = lane & 31;
    const int y0   = rowblk * 2;
    const int y    = y0 + (wave >> 1);
    const int x0   = (wave & 1) * 128 + (tx << 2);
    const int c0   = half * NCH;

    const bool ym = YEDGE ? (y > 0) : true;
    const bool yp = YEDGE ? (y < HH - 1) : true;
    const bool xl = x0 > 0, xr = x0 < WW - 4;
    const bool rowok[3] = { ym, true, yp };
    const bool colok[6] = { xl, true, true, true, true, xr };

    const float* Fb = F + (size_t)b * IMGSZ;
    int arow = y0 - 1 + wave;
    if (YEDGE) arow = arow < 0 ? 0 : (arow > HH - 1 ? HH - 1 : arow);
    const float* gsrc0 = Fb + arow * WW + (lane << 2);
    char* ldst0 = slabb + wave * 1024;

    const int rbase = half * 4096 + (wave >> 1) * 1024;
    const int bM = rbase + x0 * 4;
    const int bL = rbase + (xl ? x0 * 4 - 4 : 0);
    const int bR = rbase + (xr ? x0 * 4 + 16 : 1020);
    const bool edge = (tx == 0) || (tx == 31);
    const int bE = (tx == 31) ? bR : bL;

    float sq[3][6];
    float dotv[8][4];
#pragma unroll
    for (int r = 0; r < 3; ++r)
#pragma unroll
        for (int j = 0; j < 6; ++j) sq[r][j] = 0.f;
#pragma unroll
    for (int d = 0; d < 8; ++d)
#pragma unroll
        for (int i = 0; i < 4; ++i) dotv[d][i] = 0.f;

    STAGE(0) STAGE(1) STAGE(2)

#pragma unroll 1
    for (int g = 0; g < 16; ++g) {
        WAITB(4)
        STAGE(g + 3)
        float v[3][6];
        LOADV(g, v)
        acc_pass1(v, sq, dotv);
    }

#pragma unroll
    for (int r = 0; r < 3; ++r)
#pragma unroll
        for (int j = 0; j < 6; ++j) sq[r][j] += __shfl_xor(sq[r][j], 32);
#pragma unroll
    for (int d = 0; d < 8; ++d)
#pragma unroll
        for (int i = 0; i < 4; ++i) dotv[d][i] += __shfl_xor(dotv[d][i], 32);

    float nrm[3][6];
#pragma unroll
    for (int r = 0; r < 3; ++r)
#pragma unroll
        for (int j = 0; j < 6; ++j) nrm[r][j] = __builtin_amdgcn_sqrtf(sq[r][j]);

    float w[8][4];
    float simarr[4];
#pragma unroll
    for (int i = 0; i < 4; ++i) {
        float s[8];
        const float cn = nrm[1][i + 1];
        float tot = 0.f, cnt = 0.f;
        int d = 0;
#pragma unroll
        for (int dyi = 0; dyi < 3; ++dyi)
#pragma unroll
            for (int dxi = 0; dxi < 3; ++dxi) {
                if (dyi == 1 && dxi == 1) continue;
                const bool m = rowok[dyi] && colok[i + dxi];
                const float den = fmaxf(cn * nrm[dyi][i + dxi], EPSV);
                const float cs = dotv[d][i] * __builtin_amdgcn_rcpf(den);
                s[d] = m ? cs : 0.f;
                tot += s[d];
                cnt += m ? 1.f : 0.f;
                ++d;
            }
        simarr[i] = tot * __builtin_amdgcn_rcpf(cnt);
        {
            float mx = s[0];
#pragma unroll
            for (int d2 = 1; d2 < 8; ++d2) mx = fmaxf(mx, s[d2]);
            float wsum = 0.f;
#pragma unroll
            for (int d2 = 0; d2 < 8; ++d2) { w[d2][i] = __expf(s[d2] - mx); wsum += w[d2][i]; }
            const float inv = __builtin_amdgcn_rcpf(wsum);
#pragma unroll
            for (int d2 = 0; d2 < 8; ++d2) w[d2][i] *= inv;
        }
    }
    if (half == 0) {
        float4 simv = { simarr[0], simarr[1], simarr[2], simarr[3] };
        *reinterpret_cast<float4*>(simout + b * HWSZ + y * WW + x0) = simv;
    }

    {
        unsigned short* outp = Fn + (size_t)b * IMGSZ + (size_t)c0 * HWSZ + y * WW + x0;
#pragma unroll 1
        for (int g = 16; g < 29; ++g) {
            WAITB(4)
            STAGE(g + 3)
            float v[3][6];
            LOADV(g, v)
            float o[4] = { 0.f, 0.f, 0.f, 0.f };
            acc_pass2(v, w, o);
            uint2 ov; ov.x = pkh(o[0], o[1]); ov.y = pkh(o[2], o[3]);
            *reinterpret_cast<uint2*>(outp + (g & 15) * HWSZ) = ov;
        }
        { WAITB(4) float v[3][6]; LOADV(29, v)
          float o[4] = { 0.f, 0.f, 0.f, 0.f }; acc_pass2(v, w, o);
          uint2 ov; ov.x = pkh(o[0], o[1]); ov.y = pkh(o[2], o[3]);
          *reinterpret_cast<uint2*>(outp + 13 * HWSZ) = ov; }
        { WAITB(2) float v[3][6]; LOADV(30, v)
          float o[4] = { 0.f, 0.f, 0.f, 0.f }; acc_pass2(v, w, o);
          uint2 ov; ov.x = pkh(o[0], o[1]); ov.y = pkh(o[2], o[3]);
          *reinterpret_cast<uint2*>(outp + 14 * HWSZ) = ov; }
        { WAITB(0) float v[3][6]; LOADV(31, v)
          float o[4] = { 0.f, 0.f, 0.f, 0.f }; acc_pass2(v, w, o);
          uint2 ov; ov.x = pkh(o[0], o[1]); ov.y = pkh(o[2], o[3]);
          *reinterpret_cast<uint2*>(outp + 15 * HWSZ) = ov; }
    }
}

__global__ __launch_bounds__(256, 4) void step1_kernel(const float* __restrict__ F,
                                                       unsigned short* __restrict__ Fn,
                                                       float* __restrict__ simout)
{
    const int linear = blockIdx.y * (HH / 2) + blockIdx.x;
    const int remap  = (linear & 7) * 128 + (linear >> 3);
    const int b      = remap >> 7;
    const int rowblk = remap & 127;

    __shared__ float4 slab4[2048];   // 32 KB

    if (rowblk != 0 && rowblk != 127)
        step1_body<false>(F, Fn, simout, (char*)slab4, b, rowblk, threadIdx.x);
    else
        step1_body<true>(F, Fn, simout, (char*)slab4, b, rowblk, threadIdx.x);
}

// ===================== STEPS 2,3: fp16 input, channel-PAIR per barrier ======
// Channel slot = [half2][row4][256 fp16] = 4 KB. Pair-slot = 8 KB; 3 pair-
// slots = 24 KB (4 blocks/CU retained). One wait+barrier per 2 channels.

#define STAGE_P(P) { \
    const int ps_ = ((P) % 3) * 8192; \
    gload16(gsrcH + (size_t)(2 * ((P) & 7)     + halfS * 16) * HWSZ, ldstH + ps_); \
    gload16(gsrcH + (size_t)(2 * ((P) & 7) + 1 + halfS * 16) * HWSZ, ldstH + ps_ + 4096); }

#define LOADV_H(SB, VV) { \
    const char* sp_ = slabb + (SB); \
    _Pragma("unroll") \
    for (int r_ = 0; r_ < 3; ++r_) { \
        uint2 b_ = *(const uint2*)(sp_ + bMH + r_ * 512); \
        float e_ = 0.f; \
        if (edge && eok) { \
            unsigned eu_ = *(const unsigned*)(sp_ + bEH + r_ * 512); \
            e_ = (tx == 31) ? cvtlo(eu_) : cvthi(eu_); \
        } \
        const unsigned lu32_ = __shfl_up(b_.y, 1); \
        const unsigned rd32_ = __shfl_down(b_.x, 1); \
        const bool ok_ = rowok[r_]; \
        VV[r_][0] = (ok_ && xl) ? ((tx == 0)  ? e_ : cvthi(lu32_)) : 0.f; \
        VV[r_][1] = ok_ ? cvtlo(b_.x) : 0.f; \
        VV[r_][2] = ok_ ? cvthi(b_.x) : 0.f; \
        VV[r_][3] = ok_ ? cvtlo(b_.y) : 0.f; \
        VV[r_][4] = ok_ ? cvthi(b_.y) : 0.f; \
        VV[r_][5] = (ok_ && xr) ? ((tx == 31) ? e_ : cvtlo(rd32_)) : 0.f; \
    } }

template <bool YEDGE, bool COMPUTE_NEXT>
__device__ __forceinline__ void steph_body(const unsigned short* __restrict__ F,
                                           unsigned short* __restrict__ Fn,
                                           float* __restrict__ simout,
                                           char* slabb, int b, int rowblk, int tid)
{
    const int wave = tid >> 6;
    const int lane = tid & 63;
    const int half = lane >> 5;
    const int tx   = lane & 31;
    const int y0   = rowblk * 2;
    const int y    = y0 + (wave >> 1);
    const int x0   = (wave & 1) * 128 + (tx << 2);
    const int c0   = half * NCH;

    const bool ym = YEDGE ? (y > 0) : true;
    const bool yp = YEDGE ? (y < HH - 1) : true;
    const bool xl = x0 > 0, xr = x0 < WW - 4;
    const bool rowok[3] = { ym, true, yp };
    const bool colok[6] = { xl, true, true, true, true, xr };

    const unsigned short* Fb = F + (size_t)b * IMGSZ;

    // Staging role: wave = (halfS, rowpair). One gload16 = 2 fp16 rows (1 KB).
    const int halfS = wave >> 1;
    const int rp    = wave & 1;
    int srow = y0 - 1 + 2 * rp;
    int dsh  = 0;
    if (YEDGE) {
        if (srow < 0)               { srow = 0;      dsh = 512;  }
        else if (srow + 1 > HH - 1) { srow = HH - 2; dsh = -512; }
    }
    const unsigned short* gsrcH = Fb + srow * WW + lane * 8;
    char* ldstH = slabb + halfS * 2048 + rp * 1024 + dsh;

    const int bMH = half * 2048 + (wave >> 1) * 512 + x0 * 2;
    const bool edge = (tx == 0) || (tx == 31);
    const bool eok  = (tx == 31) ? xr : xl;
    const int bEH   = (tx == 31) ? (bMH + 8) : (bMH - 4);

    float sq[3][6];
    float dotv[8][4];
#pragma unroll
    for (int r = 0; r < 3; ++r)
#pragma unroll
        for (int j = 0; j < 6; ++j) sq[r][j] = 0.f;
#pragma unroll
    for (int d = 0; d < 8; ++d)
#pragma unroll
        for (int i = 0; i < 4; ++i) dotv[d][i] = 0.f;

    STAGE_P(0) STAGE_P(1)

#pragma unroll 1
    for (int p = 0; p < (COMPUTE_NEXT ? 8 : 6); ++p) {
        WAITB(2)
        const int sb = (p % 3) * 8192;
        { float v[3][6]; LOADV_H(sb, v)        acc_pass1(v, sq, dotv); }
        { float v[3][6]; LOADV_H(sb + 4096, v) acc_pass1(v, sq, dotv); }
        STAGE_P(p + 2)                 // p=6,7 stage pairs 8,9 = pass-2 ch 0..3
    }
    if (!COMPUTE_NEXT) {               // peel pairs 6,7
        { WAITB(2) const int sb = 0;   // 6%3=0
          float v[3][6]; LOADV_H(sb, v)        acc_pass1(v, sq, dotv);
          { float u[3][6]; LOADV_H(sb + 4096, u) acc_pass1(u, sq, dotv); } }
        { WAITB(0) const int sb = 8192; // 7%3=1
          float v[3][6]; LOADV_H(sb, v)        acc_pass1(v, sq, dotv);
          { float u[3][6]; LOADV_H(sb + 4096, u) acc_pass1(u, sq, dotv); } }
    }

#pragma unroll
    for (int r = 0; r < 3; ++r)
#pragma unroll
        for (int j = 0; j < 6; ++j) sq[r][j] += __shfl_xor(sq[r][j], 32);
#pragma unroll
    for (int d = 0; d < 8; ++d)
#pragma unroll
        for (int i = 0; i < 4; ++i) dotv[d][i] += __shfl_xor(dotv[d][i], 32);

    float nrm[3][6];
#pragma unroll
    for (int r = 0; r < 3; ++r)
#pragma unroll
        for (int j = 0; j < 6; ++j) nrm[r][j] = __builtin_amdgcn_sqrtf(sq[r][j]);

    float w[8][4];
    float simarr[4];
#pragma unroll
    for (int i = 0; i < 4; ++i) {
        float s[8];
        const float cn = nrm[1][i + 1];
        float tot = 0.f, cnt = 0.f;
        int d = 0;
#pragma unroll
        for (int dyi = 0; dyi < 3; ++dyi)
#pragma unroll
            for (int dxi = 0; dxi < 3; ++dxi) {
                if (dyi == 1 && dxi == 1) continue;
                const bool m = rowok[dyi] && colok[i + dxi];
                const float den = fmaxf(cn * nrm[dyi][i + dxi], EPSV);
                const float cs = dotv[d][i] * __builtin_amdgcn_rcpf(den);
                s[d] = m ? cs : 0.f;
                tot += s[d];
                cnt += m ? 1.f : 0.f;
                ++d;
            }
        simarr[i] = tot * __builtin_amdgcn_rcpf(cnt);
        if (COMPUTE_NEXT) {
            float mx = s[0];
#pragma unroll
            for (int d2 = 1; d2 < 8; ++d2) mx = fmaxf(mx, s[d2]);
            float wsum = 0.f;
#pragma unroll
            for (int d2 = 0; d2 < 8; ++d2) { w[d2][i] = __expf(s[d2] - mx); wsum += w[d2][i]; }
            const float inv = __builtin_amdgcn_rcpf(wsum);
#pragma unroll
            for (int d2 = 0; d2 < 8; ++d2) w[d2][i] *= inv;
        }
    }
    if (half == 0) {
        float4 simv = { simarr[0], simarr[1], simarr[2], simarr[3] };
        *reinterpret_cast<float4*>(simout + b * HWSZ + y * WW + x0) = simv;
    }

    // Pass 2: pairs 8..15 (channels 0..15 re-staged). FIFO-derived vmcnt:
    // first pair 3 (sim-store in flight), steady 4 (2 stores + 2 stages), peel 4/2.
    if (COMPUTE_NEXT) {
        unsigned short* outp = Fn + (size_t)b * IMGSZ + (size_t)c0 * HWSZ + y * WW + x0;

#define PASS2_PAIR(P) { \
            const int sb_ = ((P) % 3) * 8192; \
            const int ch_ = 2 * ((P) & 7); \
            { float v[3][6]; LOADV_H(sb_, v) \
              float o[4] = { 0.f, 0.f, 0.f, 0.f }; acc_pass2(v, w, o); \
              uint2 ov; ov.x = pkh(o[0], o[1]); ov.y = pkh(o[2], o[3]); \
              *reinterpret_cast<uint2*>(outp + ch_ * HWSZ) = ov; } \
            { float v[3][6]; LOADV_H(sb_ + 4096, v) \
              float o[4] = { 0.f, 0.f, 0.f, 0.f }; acc_pass2(v, w, o); \
              uint2 ov; ov.x = pkh(o[0], o[1]); ov.y = pkh(o[2], o[3]); \
              *reinterpret_cast<uint2*>(outp + (ch_ + 1) * HWSZ) = ov; } }

        { WAITB(3) PASS2_PAIR(8) STAGE_P(10) }
#pragma unroll 1
        for (int p = 9; p < 14; ++p) {
            WAITB(4)
            PASS2_PAIR(p)
            STAGE_P(p + 2)
        }
        { WAITB(4) PASS2_PAIR(14) }
        { WAITB(2) PASS2_PAIR(15) }
#undef PASS2_PAIR
    }
}

template <bool COMPUTE_NEXT>
__global__ __launch_bounds__(256, 4) void steph_kernel(const unsigned short* __restrict__ F,
                                                       unsigned short* __restrict__ Fn,
                                                       float* __restrict__ simout)
{
    const int linear = blockIdx.y * (HH / 2) + blockIdx.x;
    const int remap  = (linear & 7) * 128 + (linear >> 3);
    const int b      = remap >> 7;
    const int rowblk = remap & 127;

    __shared__ float4 slabH[1536];   // 24 KB: 3 pair-slots

    if (rowblk != 0 && rowblk != 127)
        steph_body<false, COMPUTE_NEXT>(F, Fn, simout, (char*)slabH, b, rowblk, threadIdx.x);
    else
        steph_body<true,  COMPUTE_NEXT>(F, Fn, simout, (char*)slabH, b, rowblk, threadIdx.x);
}

// out[g][t][p] = 0.25 * sum_{i<4} sims[tt][4g+i][p], tt = {0,0,1,2}[t]
__global__ __launch_bounds__(256) void reduce_kernel(const float* __restrict__ sims,
                                                     float* __restrict__ out)
{
    const int idx = blockIdx.x * blockDim.x + threadIdx.x;
    const int p4 = idx & (HWSZ / 4 - 1);
    const int t  = (idx >> 14) & 3;
    const int g  = idx >> 16;
    const int tt = (t <= 1) ? 0 : (t - 1);
    const float4* s = reinterpret_cast<const float4*>(sims) +
                      (size_t)(tt * NIMG + g * 4) * (HWSZ / 4) + p4;
    float4 a = s[0];
    float4 b = s[HWSZ / 4];
    float4 c = s[2 * (HWSZ / 4)];
    float4 d = s[3 * (HWSZ / 4)];
    float4 o;
    o.x = 0.25f * (a.x + b.x + c.x + d.x);
    o.y = 0.25f * (a.y + b.y + c.y + d.y);
    o.z = 0.25f * (a.z + b.z + c.z + d.z);
    o.w = 0.25f * (a.w + b.w + c.w + d.w);
    reinterpret_cast<float4*>(out)[idx] = o;
}

extern "C" void kernel_launch(void* const* d_in, const int* in_sizes, int n_in,
                              void* d_out, int out_size, void* d_ws, size_t ws_size,
                              hipStream_t stream)
{
    const float* F0 = (const float*)d_in[0];
    unsigned short* F1h = (unsigned short*)d_ws;                 // 32 MB fp16
    unsigned short* F2h = F1h + (size_t)NIMG * IMGSZ;            // 32 MB fp16
    float* sims = (float*)(F2h + (size_t)NIMG * IMGSZ);          // 6 MB f32

    dim3 block(256);
    dim3 grid(HH / 2, NIMG);

    hipLaunchKernelGGL(step1_kernel,          grid, block, 0, stream, F0, F1h, sims);
    hipLaunchKernelGGL((steph_kernel<true>),  grid, block, 0, stream, F1h, F2h, sims + (size_t)NIMG * HWSZ);
    hipLaunchKernelGGL((steph_kernel<false>), grid, block, 0, stream, F2h, nullptr, sims + (size_t)2 * NIMG * HWSZ);

    hipLaunchKernelGGL(reduce_kernel, dim3((2 * 4 * HWSZ / 4) / 256), block, 0, stream,
                       sims, (float*)d_out);
}

// Round 20
// 96.069 us; speedup vs baseline: 1.1325x; 1.0008x over previous
//
#include <hip/hip_runtime.h>
#include <hip/hip_fp16.h>

#define HH 256
#define WW 256
#define CC 32
#define HWSZ (HH * WW)
#define IMGSZ (CC * HWSZ)
#define NIMG 8
#define EPSV 1e-8f
#define NCH (CC / 2)   // channels per lane (2-way channel split)

__device__ __forceinline__ void acc_pass1(const float v[3][6],
                                          float sq[3][6], float dotv[8][4])
{
#pragma unroll
    for (int r = 0; r < 3; ++r)
#pragma unroll
        for (int j = 0; j < 6; ++j) sq[r][j] = fmaf(v[r][j], v[r][j], sq[r][j]);
    int d = 0;
#pragma unroll
    for (int dyi = 0; dyi < 3; ++dyi)
#pragma unroll
        for (int dxi = 0; dxi < 3; ++dxi) {
            if (dyi == 1 && dxi == 1) continue;
#pragma unroll
            for (int i = 0; i < 4; ++i)
                dotv[d][i] = fmaf(v[1][i + 1], v[dyi][i + dxi], dotv[d][i]);
            ++d;
        }
}

__device__ __forceinline__ void acc_pass2(const float v[3][6],
                                          const float w[8][4], float o[4])
{
    int d = 0;
#pragma unroll
    for (int dyi = 0; dyi < 3; ++dyi)
#pragma unroll
        for (int dxi = 0; dxi < 3; ++dxi) {
            if (dyi == 1 && dxi == 1) continue;
#pragma unroll
            for (int i = 0; i < 4; ++i)
                o[i] = fmaf(w[d][i], v[dyi][i + dxi], o[i]);
            ++d;
        }
}

__device__ __forceinline__ void gload16(const void* g, void* l)
{
    __builtin_amdgcn_global_load_lds(
        (const __attribute__((address_space(1))) void*)g,
        (__attribute__((address_space(3))) void*)l, 16, 0, 0);
}

__device__ __forceinline__ float cvtlo(unsigned u)
{ return __half2float(__ushort_as_half((unsigned short)(u & 0xffffu))); }
__device__ __forceinline__ float cvthi(unsigned u)
{ return __half2float(__ushort_as_half((unsigned short)(u >> 16))); }
__device__ __forceinline__ unsigned pkh(float a, float b)
{
    return (unsigned)__half_as_ushort(__float2half_rn(a)) |
           ((unsigned)__half_as_ushort(__float2half_rn(b)) << 16);
}

#define WAITB(VM) { asm volatile("s_waitcnt vmcnt(" #VM ")" ::: "memory"); \
                    __builtin_amdgcn_s_barrier(); }

// ===================== STEP 1: f32 input -> fp16 output =====================
// 5 slabs (40 KB), stage distance 4 (~840 cyc cover for cold-HBM reads).
// vmcnt derived from FIFO (loads+stores, issue order).

#define STAGE(SLOT) { \
    const int ch_ = (SLOT) & 15; \
    const int bo_ = ((SLOT) % 5) * 8192; \
    gload16(gsrc0 + (size_t)ch_ * HWSZ,        ldst0 + bo_); \
    gload16(gsrc0 + (size_t)(ch_ + 16) * HWSZ, ldst0 + bo_ + 4096); }

#define LOADV(G, VV) { \
    const char* sp_ = slabb + ((G) % 5) * 8192; \
    _Pragma("unroll") \
    for (int r_ = 0; r_ < 3; ++r_) { \
        float4 m_ = *(const float4*)(sp_ + bM + r_ * 1024); \
        float e_ = 0.f; \
        if (edge) e_ = *(const float*)(sp_ + bE + r_ * 1024); \
        const float lu_ = __shfl_up(m_.w, 1); \
        const float rd_ = __shfl_down(m_.x, 1); \
        const bool ok_ = rowok[r_]; \
        VV[r_][0] = (ok_ && xl) ? ((tx == 0)  ? e_ : lu_) : 0.f; \
        VV[r_][1] = ok_ ? m_.x : 0.f; \
        VV[r_][2] = ok_ ? m_.y : 0.f; \
        VV[r_][3] = ok_ ? m_.z : 0.f; \
        VV[r_][4] = ok_ ? m_.w : 0.f; \
        VV[r_][5] = (ok_ && xr) ? ((tx == 31) ? e_ : rd_) : 0.f; \
    } }

#define P2STORE(G) { \
    float v[3][6]; LOADV(G, v) \
    float o[4] = { 0.f, 0.f, 0.f, 0.f }; acc_pass2(v, w, o); \
    uint2 ov; ov.x = pkh(o[0], o[1]); ov.y = pkh(o[2], o[3]); \
    *reinterpret_cast<uint2*>(outp + ((G) & 15) * HWSZ) = ov; }

template <bool YEDGE>
__device__ __forceinline__ void step1_body(const float* __restrict__ F,
                                           unsigned short* __restrict__ Fn,
                                           float* __restrict__ simout,
                                           char* slabb, int b, int rowblk, int tid)
{
    const int wave = tid >> 6;
    const int lane = tid & 63;
    const int half = lane >> 5;
    const int tx   = lane & 31;
    const int y0   = rowblk * 2;
    const int y    = y0 + (wave >> 1);
    const int x0   = (wave & 1) * 128 + (tx << 2);
    const int c0   = half * NCH;

    const bool ym = YEDGE ? (y > 0) : true;
    const bool yp = YEDGE ? (y < HH - 1) : true;
    const bool xl = x0 > 0, xr = x0 < WW - 4;
    const bool rowok[3] = { ym, true, yp };
    const bool colok[6] = { xl, true, true, true, true, xr };

    const float* Fb = F + (size_t)b * IMGSZ;
    int arow = y0 - 1 + wave;
    if (YEDGE) arow = arow < 0 ? 0 : (arow > HH - 1 ? HH - 1 : arow);
    const float* gsrc0 = Fb + arow * WW + (lane << 2);
    char* ldst0 = slabb + wave * 1024;

    const int rbase = half * 4096 + (wave >> 1) * 1024;
    const int bM = rbase + x0 * 4;
    const int bL = rbase + (xl ? x0 * 4 - 4 : 0);
    const int bR = rbase + (xr ? x0 * 4 + 16 : 1020);
    const bool edge = (tx == 0) || (tx == 31);
    const int bE = (tx == 31) ? bR : bL;

    float sq[3][6];
    float dotv[8][4];
#pragma unroll
    for (int r = 0; r < 3; ++r)
#pragma unroll
        for (int j = 0; j < 6; ++j) sq[r][j] = 0.f;
#pragma unroll
    for (int d = 0; d < 8; ++d)
#pragma unroll
        for (int i = 0; i < 4; ++i) dotv[d][i] = 0.f;

    STAGE(0) STAGE(1) STAGE(2) STAGE(3)

#pragma unroll 1
    for (int g = 0; g < 16; ++g) {
        WAITB(6)
        STAGE(g + 4)                   // slots 4..19; g=12..15 prefetch pass-2 ch 0..3
        float v[3][6];
        LOADV(g, v)
        acc_pass1(v, sq, dotv);
    }

#pragma unroll
    for (int r = 0; r < 3; ++r)
#pragma unroll
        for (int j = 0; j < 6; ++j) sq[r][j] += __shfl_xor(sq[r][j], 32);
#pragma unroll
    for (int d = 0; d < 8; ++d)
#pragma unroll
        for (int i = 0; i < 4; ++i) dotv[d][i] += __shfl_xor(dotv[d][i], 32);

    float nrm[3][6];
#pragma unroll
    for (int r = 0; r < 3; ++r)
#pragma unroll
        for (int j = 0; j < 6; ++j) nrm[r][j] = __builtin_amdgcn_sqrtf(sq[r][j]);

    float w[8][4];
    float simarr[4];
#pragma unroll
    for (int i = 0; i < 4; ++i) {
        float s[8];
        const float cn = nrm[1][i + 1];
        float tot = 0.f, cnt = 0.f;
        int d = 0;
#pragma unroll
        for (int dyi = 0; dyi < 3; ++dyi)
#pragma unroll
            for (int dxi = 0; dxi < 3; ++dxi) {
                if (dyi == 1 && dxi == 1) continue;
                const bool m = rowok[dyi] && colok[i + dxi];
                const float den = fmaxf(cn * nrm[dyi][i + dxi], EPSV);
                const float cs = dotv[d][i] * __builtin_amdgcn_rcpf(den);
                s[d] = m ? cs : 0.f;
                tot += s[d];
                cnt += m ? 1.f : 0.f;
                ++d;
            }
        simarr[i] = tot * __builtin_amdgcn_rcpf(cnt);
        {
            float mx = s[0];
#pragma unroll
            for (int d2 = 1; d2 < 8; ++d2) mx = fmaxf(mx, s[d2]);
            float wsum = 0.f;
#pragma unroll
            for (int d2 = 0; d2 < 8; ++d2) { w[d2][i] = __expf(s[d2] - mx); wsum += w[d2][i]; }
            const float inv = __builtin_amdgcn_rcpf(wsum);
#pragma unroll
            for (int d2 = 0; d2 < 8; ++d2) w[d2][i] *= inv;
        }
    }
    if (half == 0) {
        float4 simv = { simarr[0], simarr[1], simarr[2], simarr[3] };
        *reinterpret_cast<float4*>(simout + b * HWSZ + y * WW + x0) = simv;
    }

    // Pass 2: slots 16..31. vmcnt ramp 7/8/9 -> steady 10 -> peels 10/8/6/4
    // (exact FIFO counts incl. the sim-store and per-iter uint2 stores).
    {
        unsigned short* outp = Fn + (size_t)b * IMGSZ + (size_t)c0 * HWSZ + y * WW + x0;
        { WAITB(7)  STAGE(20) P2STORE(16) }
        { WAITB(8)  STAGE(21) P2STORE(17) }
        { WAITB(9)  STAGE(22) P2STORE(18) }
#pragma unroll 1
        for (int g = 19; g < 28; ++g) {
            WAITB(10)
            STAGE(g + 4)               // 23..31
            P2STORE(g)
        }
        { WAITB(10) P2STORE(28) }
        { WAITB(8)  P2STORE(29) }
        { WAITB(6)  P2STORE(30) }
        { WAITB(4)  P2STORE(31) }
    }
}

__global__ __launch_bounds__(256, 4) void step1_kernel(const float* __restrict__ F,
                                                       unsigned short* __restrict__ Fn,
                                                       float* __restrict__ simout)
{
    const int linear = blockIdx.y * (HH / 2) + blockIdx.x;
    const int remap  = (linear & 7) * 128 + (linear >> 3);
    const int b      = remap >> 7;
    const int rowblk = remap & 127;

    __shared__ float4 slab4[2560];   // 40 KB: 5 slabs

    if (rowblk != 0 && rowblk != 127)
        step1_body<false>(F, Fn, simout, (char*)slab4, b, rowblk, threadIdx.x);
    else
        step1_body<true>(F, Fn, simout, (char*)slab4, b, rowblk, threadIdx.x);
}

// ===================== STEPS 2,3: fp16 input, channel-PAIR per barrier ======
// (R18-verbatim: 3 pair-slots = 24 KB, one wait+barrier per 2 channels.)

#define STAGE_P(P) { \
    const int ps_ = ((P) % 3) * 8192; \
    gload16(gsrcH + (size_t)(2 * ((P) & 7)     + halfS * 16) * HWSZ, ldstH + ps_); \
    gload16(gsrcH + (size_t)(2 * ((P) & 7) + 1 + halfS * 16) * HWSZ, ldstH + ps_ + 4096); }

#define LOADV_H(SB, VV) { \
    const char* sp_ = slabb + (SB); \
    _Pragma("unroll") \
    for (int r_ = 0; r_ < 3; ++r_) { \
        uint2 b_ = *(const uint2*)(sp_ + bMH + r_ * 512); \
        float e_ = 0.f; \
        if (edge && eok) { \
            unsigned eu_ = *(const unsigned*)(sp_ + bEH + r_ * 512); \
            e_ = (tx == 31) ? cvtlo(eu_) : cvthi(eu_); \
        } \
        const unsigned lu32_ = __shfl_up(b_.y, 1); \
        const unsigned rd32_ = __shfl_down(b_.x, 1); \
        const bool ok_ = rowok[r_]; \
        VV[r_][0] = (ok_ && xl) ? ((tx == 0)  ? e_ : cvthi(lu32_)) : 0.f; \
        VV[r_][1] = ok_ ? cvtlo(b_.x) : 0.f; \
        VV[r_][2] = ok_ ? cvthi(b_.x) : 0.f; \
        VV[r_][3] = ok_ ? cvtlo(b_.y) : 0.f; \
        VV[r_][4] = ok_ ? cvthi(b_.y) : 0.f; \
        VV[r_][5] = (ok_ && xr) ? ((tx == 31) ? e_ : cvtlo(rd32_)) : 0.f; \
    } }

template <bool YEDGE, bool COMPUTE_NEXT>
__device__ __forceinline__ void steph_body(const unsigned short* __restrict__ F,
                                           unsigned short* __restrict__ Fn,
                                           float* __restrict__ simout,
                                           char* slabb, int b, int rowblk, int tid)
{
    const int wave = tid >> 6;
    const int lane = tid & 63;
    const int half = lane >> 5;
    const int tx   = lane & 31;
    const int y0   = rowblk * 2;
    const int y    = y0 + (wave >> 1);
    const int x0   = (wave & 1) * 128 + (tx << 2);
    const int c0   = half * NCH;

    const bool ym = YEDGE ? (y > 0) : true;
    const bool yp = YEDGE ? (y < HH - 1) : true;
    const bool xl = x0 > 0, xr = x0 < WW - 4;
    const bool rowok[3] = { ym, true, yp };
    const bool colok[6] = { xl, true, true, true, true, xr };

    const unsigned short* Fb = F + (size_t)b * IMGSZ;

    const int halfS = wave >> 1;
    const int rp    = wave & 1;
    int srow = y0 - 1 + 2 * rp;
    int dsh  = 0;
    if (YEDGE) {
        if (srow < 0)               { srow = 0;      dsh = 512;  }
        else if (srow + 1 > HH - 1) { srow = HH - 2; dsh = -512; }
    }
    const unsigned short* gsrcH = Fb + srow * WW + lane * 8;
    char* ldstH = slabb + halfS * 2048 + rp * 1024 + dsh;

    const int bMH = half * 2048 + (wave >> 1) * 512 + x0 * 2;
    const bool edge = (tx == 0) || (tx == 31);
    const bool eok  = (tx == 31) ? xr : xl;
    const int bEH   = (tx == 31) ? (bMH + 8) : (bMH - 4);

    float sq[3][6];
    float dotv[8][4];
#pragma unroll
    for (int r = 0; r < 3; ++r)
#pragma unroll
        for (int j = 0; j < 6; ++j) sq[r][j] = 0.f;
#pragma unroll
    for (int d = 0; d < 8; ++d)
#pragma unroll
        for (int i = 0; i < 4; ++i) dotv[d][i] = 0.f;

    STAGE_P(0) STAGE_P(1)

#pragma unroll 1
    for (int p = 0; p < (COMPUTE_NEXT ? 8 : 6); ++p) {
        WAITB(2)
        const int sb = (p % 3) * 8192;
        { float v[3][6]; LOADV_H(sb, v)        acc_pass1(v, sq, dotv); }
        { float v[3][6]; LOADV_H(sb + 4096, v) acc_pass1(v, sq, dotv); }
        STAGE_P(p + 2)
    }
    if (!COMPUTE_NEXT) {
        { WAITB(2) const int sb = 0;
          float v[3][6]; LOADV_H(sb, v)        acc_pass1(v, sq, dotv);
          { float u[3][6]; LOADV_H(sb + 4096, u) acc_pass1(u, sq, dotv); } }
        { WAITB(0) const int sb = 8192;
          float v[3][6]; LOADV_H(sb, v)        acc_pass1(v, sq, dotv);
          { float u[3][6]; LOADV_H(sb + 4096, u) acc_pass1(u, sq, dotv); } }
    }

#pragma unroll
    for (int r = 0; r < 3; ++r)
#pragma unroll
        for (int j = 0; j < 6; ++j) sq[r][j] += __shfl_xor(sq[r][j], 32);
#pragma unroll
    for (int d = 0; d < 8; ++d)
#pragma unroll
        for (int i = 0; i < 4; ++i) dotv[d][i] += __shfl_xor(dotv[d][i], 32);

    float nrm[3][6];
#pragma unroll
    for (int r = 0; r < 3; ++r)
#pragma unroll
        for (int j = 0; j < 6; ++j) nrm[r][j] = __builtin_amdgcn_sqrtf(sq[r][j]);

    float w[8][4];
    float simarr[4];
#pragma unroll
    for (int i = 0; i < 4; ++i) {
        float s[8];
        const float cn = nrm[1][i + 1];
        float tot = 0.f, cnt = 0.f;
        int d = 0;
#pragma unroll
        for (int dyi = 0; dyi < 3; ++dyi)
#pragma unroll
            for (int dxi = 0; dxi < 3; ++dxi) {
                if (dyi == 1 && dxi == 1) continue;
                const bool m = rowok[dyi] && colok[i + dxi];
                const float den = fmaxf(cn * nrm[dyi][i + dxi], EPSV);
                const float cs = dotv[d][i] * __builtin_amdgcn_rcpf(den);
                s[d] = m ? cs : 0.f;
                tot += s[d];
                cnt += m ? 1.f : 0.f;
                ++d;
            }
        simarr[i] = tot * __builtin_amdgcn_rcpf(cnt);
        if (COMPUTE_NEXT) {
            float mx = s[0];
#pragma unroll
            for (int d2 = 1; d2 < 8; ++d2) mx = fmaxf(mx, s[d2]);
            float wsum = 0.f;
#pragma unroll
            for (int d2 = 0; d2 < 8; ++d2) { w[d2][i] = __expf(s[d2] - mx); wsum += w[d2][i]; }
            const float inv = __builtin_amdgcn_rcpf(wsum);
#pragma unroll
            for (int d2 = 0; d2 < 8; ++d2) w[d2][i] *= inv;
        }
    }
    if (half == 0) {
        float4 simv = { simarr[0], simarr[1], simarr[2], simarr[3] };
        *reinterpret_cast<float4*>(simout + b * HWSZ + y * WW + x0) = simv;
    }

    if (COMPUTE_NEXT) {
        unsigned short* outp = Fn + (size_t)b * IMGSZ + (size_t)c0 * HWSZ + y * WW + x0;

#define PASS2_PAIR(P) { \
            const int sb_ = ((P) % 3) * 8192; \
            const int ch_ = 2 * ((P) & 7); \
            { float v[3][6]; LOADV_H(sb_, v) \
              float o[4] = { 0.f, 0.f, 0.f, 0.f }; acc_pass2(v, w, o); \
              uint2 ov; ov.x = pkh(o[0], o[1]); ov.y = pkh(o[2], o[3]); \
              *reinterpret_cast<uint2*>(outp + ch_ * HWSZ) = ov; } \
            { float v[3][6]; LOADV_H(sb_ + 4096, v) \
              float o[4] = { 0.f, 0.f, 0.f, 0.f }; acc_pass2(v, w, o); \
              uint2 ov; ov.x = pkh(o[0], o[1]); ov.y = pkh(o[2], o[3]); \
              *reinterpret_cast<uint2*>(outp + (ch_ + 1) * HWSZ) = ov; } }

        { WAITB(3) PASS2_PAIR(8) STAGE_P(10) }
#pragma unroll 1
        for (int p = 9; p < 14; ++p) {
            WAITB(4)
            PASS2_PAIR(p)
            STAGE_P(p + 2)
        }
        { WAITB(4) PASS2_PAIR(14) }
        { WAITB(2) PASS2_PAIR(15) }
#undef PASS2_PAIR
    }
}

template <bool COMPUTE_NEXT>
__global__ __launch_bounds__(256, 4) void steph_kernel(const unsigned short* __restrict__ F,
                                                       unsigned short* __restrict__ Fn,
                                                       float* __restrict__ simout)
{
    const int linear = blockIdx.y * (HH / 2) + blockIdx.x;
    const int remap  = (linear & 7) * 128 + (linear >> 3);
    const int b      = remap >> 7;
    const int rowblk = remap & 127;

    __shared__ float4 slabH[1536];   // 24 KB: 3 pair-slots

    if (rowblk != 0 && rowblk != 127)
        steph_body<false, COMPUTE_NEXT>(F, Fn, simout, (char*)slabH, b, rowblk, threadIdx.x);
    else
        steph_body<true,  COMPUTE_NEXT>(F, Fn, simout, (char*)slabH, b, rowblk, threadIdx.x);
}

// out[g][t][p] = 0.25 * sum_{i<4} sims[tt][4g+i][p], tt = {0,0,1,2}[t]
__global__ __launch_bounds__(256) void reduce_kernel(const float* __restrict__ sims,
                                                     float* __restrict__ out)
{
    const int idx = blockIdx.x * blockDim.x + threadIdx.x;
    const int p4 = idx & (HWSZ / 4 - 1);
    const int t  = (idx >> 14) & 3;
    const int g  = idx >> 16;
    const int tt = (t <= 1) ? 0 : (t - 1);
    const float4* s = reinterpret_cast<const float4*>(sims) +
                      (size_t)(tt * NIMG + g * 4) * (HWSZ / 4) + p4;
    float4 a = s[0];
    float4 b = s[HWSZ / 4];
    float4 c = s[2 * (HWSZ / 4)];
    float4 d = s[3 * (HWSZ / 4)];
    float4 o;
    o.x = 0.25f * (a.x + b.x + c.x + d.x);
    o.y = 0.25f * (a.y + b.y + c.y + d.y);
    o.z = 0.25f * (a.z + b.z + c.z + d.z);
    o.w = 0.25f * (a.w + b.w + c.w + d.w);
    reinterpret_cast<float4*>(out)[idx] = o;
}

extern "C" void kernel_launch(void* const* d_in, const int* in_sizes, int n_in,
                              void* d_out, int out_size, void* d_ws, size_t ws_size,
                              hipStream_t stream)
{
    const float* F0 = (const float*)d_in[0];
    unsigned short* F1h = (unsigned short*)d_ws;                 // 32 MB fp16
    unsigned short* F2h = F1h + (size_t)NIMG * IMGSZ;            // 32 MB fp16
    float* sims = (float*)(F2h + (size_t)NIMG * IMGSZ);          // 6 MB f32

    dim3 block(256);
    dim3 grid(HH / 2, NIMG);

    hipLaunchKernelGGL(step1_kernel,          grid, block, 0, stream, F0, F1h, sims);
    hipLaunchKernelGGL((steph_kernel<true>),  grid, block, 0, stream, F1h, F2h, sims + (size_t)NIMG * HWSZ);
    hipLaunchKernelGGL((steph_kernel<false>), grid, block, 0, stream, F2h, nullptr, sims + (size_t)2 * NIMG * HWSZ);

    hipLaunchKernelGGL(reduce_kernel, dim3((2 * 4 * HWSZ / 4) / 256), block, 0, stream,
                       sims, (float*)d_out);
}